// Round 1
// 105.492 us; speedup vs baseline: 1.2207x; 1.2207x over previous
//
#include <hip/hip_runtime.h>

#define NB 8
#define TE 256
#define TD 256
#define DE 512
#define QT 4

// K2 = 2*log2(e). gemm2 pre-scales its outputs by K2 so attn can exp2 directly:
// tanh(x) = 1 - 2/(exp2(K2*x)+1), and exp2(K2*(w+u)) = exp2(K2*w)*exp2(K2*u).
#define K2SCALE 2.8853900817779268f

// ---------------- GEMM: C[M,N] = K2 * A[M,K] @ W[K,N], f32, M=2048 N=K=512 -----
// BM=128 BN=64 BK=16, 256 threads, 8x4 micro-tile. grid = (8, 16, 2)
__global__ __launch_bounds__(256) void gemm2(
    const float* __restrict__ A0, const float* __restrict__ W0, float* __restrict__ C0,
    const float* __restrict__ A1, const float* __restrict__ W1, float* __restrict__ C1)
{
  constexpr int N = DE;        // 512
  constexpr int K = DE;        // 512
  constexpr int BM = 128, BN = 64, BK = 16;
  const float* A = blockIdx.z ? A1 : A0;
  const float* W = blockIdx.z ? W1 : W0;
  float*       C = blockIdx.z ? C1 : C0;
  const int tid = threadIdx.x;
  const int m0 = blockIdx.y * BM;
  const int n0 = blockIdx.x * BN;
  __shared__ float As[BK][BM];   // transposed: As[k][m]
  __shared__ float Bs[BK][BN];
  const int am = tid >> 1, ak = (tid & 1) * 8;   // A load: row am, 8 k's
  const int bk = tid >> 4, bn = (tid & 15) * 4;  // B load
  const int ty = tid >> 4, tx = tid & 15;        // micro-tile owner
  float acc[8][4];
  #pragma unroll
  for (int i = 0; i < 8; ++i)
    #pragma unroll
    for (int j = 0; j < 4; ++j) acc[i][j] = 0.f;

  for (int k0 = 0; k0 < K; k0 += BK) {
    float4 a0 = *(const float4*)(A + (size_t)(m0 + am) * K + k0 + ak);
    float4 a1 = *(const float4*)(A + (size_t)(m0 + am) * K + k0 + ak + 4);
    float4 bv = *(const float4*)(W + (size_t)(k0 + bk) * N + n0 + bn);
    __syncthreads();   // previous compute done before LDS overwrite
    As[ak + 0][am] = a0.x; As[ak + 1][am] = a0.y; As[ak + 2][am] = a0.z; As[ak + 3][am] = a0.w;
    As[ak + 4][am] = a1.x; As[ak + 5][am] = a1.y; As[ak + 6][am] = a1.z; As[ak + 7][am] = a1.w;
    *(float4*)&Bs[bk][bn] = bv;
    __syncthreads();
    #pragma unroll
    for (int k = 0; k < BK; ++k) {
      float4 av0 = *(const float4*)&As[k][ty * 8];
      float4 av1 = *(const float4*)&As[k][ty * 8 + 4];
      float4 b   = *(const float4*)&Bs[k][tx * 4];
      float a[8]  = {av0.x, av0.y, av0.z, av0.w, av1.x, av1.y, av1.z, av1.w};
      float bb[4] = {b.x, b.y, b.z, b.w};
      #pragma unroll
      for (int i = 0; i < 8; ++i)
        #pragma unroll
        for (int j = 0; j < 4; ++j)
          acc[i][j] = fmaf(a[i], bb[j], acc[i][j]);
    }
  }
  #pragma unroll
  for (int i = 0; i < 8; ++i) {
    float4 o = {acc[i][0] * K2SCALE, acc[i][1] * K2SCALE,
                acc[i][2] * K2SCALE, acc[i][3] * K2SCALE};
    *(float4*)(C + (size_t)(m0 + ty * 8 + i) * N + n0 + tx * 4) = o;
  }
}

// ---------------- fused scores + softmax + context -----------------------------
// block = 512 thr (8 waves), handles (b, q-tile of QT=4). grid = 8*64 = 512.
// ws/uh arrive pre-scaled by K2, so:
// scores[b,q,t] = Vtot - 2 * sum_f v[f] * rcp(ew[f]*eu[q][f] + 1)
// Vtot is constant over t -> drops out of softmax. Store -2*R.
__global__ __launch_bounds__(512) void attn(
    const float* __restrict__ ws, const float* __restrict__ uh,
    const float* __restrict__ enc, const float* __restrict__ va,
    float* __restrict__ out_c, float* __restrict__ out_e)
{
  const int tid  = threadIdx.x;
  const int wave = tid >> 6;
  const int lane = tid & 63;
  const int b  = blockIdx.x >> 6;          // TD/QT = 64 tiles per batch
  const int q0 = (blockIdx.x & 63) * QT;
  __shared__ float s_sc[QT][TE];           // 4 KB
  const int fbase = lane * 8;              // lane owns 8 contiguous f

  float4 v0 = *(const float4*)(va + fbase);
  float4 v1 = *(const float4*)(va + fbase + 4);
  float v[8] = {v0.x, v0.y, v0.z, v0.w, v1.x, v1.y, v1.z, v1.w};

  // eu[q][j] = exp2(K2 * Uh[b][q0+q][fbase+j])  (uh is pre-scaled by K2)
  float eu[QT][8];
  #pragma unroll
  for (int q = 0; q < QT; ++q) {
    const float* up = uh + (size_t)(b * TD + q0 + q) * DE + fbase;
    float4 u0 = *(const float4*)(up);
    float4 u1 = *(const float4*)(up + 4);
    eu[q][0] = __builtin_amdgcn_exp2f(u0.x);
    eu[q][1] = __builtin_amdgcn_exp2f(u0.y);
    eu[q][2] = __builtin_amdgcn_exp2f(u0.z);
    eu[q][3] = __builtin_amdgcn_exp2f(u0.w);
    eu[q][4] = __builtin_amdgcn_exp2f(u1.x);
    eu[q][5] = __builtin_amdgcn_exp2f(u1.y);
    eu[q][6] = __builtin_amdgcn_exp2f(u1.z);
    eu[q][7] = __builtin_amdgcn_exp2f(u1.w);
  }

  // ---- scores: wave owns t in [wave*32, wave*32+32), 1-deep prefetch on ws ----
  const int t0 = wave * 32;
  const float* wp = ws + (size_t)(b * TE + t0) * DE + fbase;
  float4 w0 = *(const float4*)(wp);
  float4 w1 = *(const float4*)(wp + 4);
  for (int t = t0; t < t0 + 32; ++t) {
    float cw[8] = {w0.x, w0.y, w0.z, w0.w, w1.x, w1.y, w1.z, w1.w};
    // prefetch next row; last iteration reads one row past (lands in uh[0],
    // still inside the same workspace allocation) and is unused.
    wp += DE;
    w0 = *(const float4*)(wp);
    w1 = *(const float4*)(wp + 4);
    float ew[8];
    #pragma unroll
    for (int j = 0; j < 8; ++j) ew[j] = __builtin_amdgcn_exp2f(cw[j]);
    float a[QT];
    #pragma unroll
    for (int q = 0; q < QT; ++q) {
      float s = 0.f;
      #pragma unroll
      for (int j = 0; j < 8; ++j) {
        float p = fmaf(ew[j], eu[q][j], 1.f);
        s = fmaf(v[j], __builtin_amdgcn_rcpf(p), s);
      }
      a[q] = s;
    }
    // value-halving butterfly: 4 partials over 64 lanes -> lane l holds q=(l&3)
    {
      const bool h1 = lane & 1;
      float m0 = h1 ? a[1] : a[0], o0 = h1 ? a[0] : a[1];
      float m1 = h1 ? a[3] : a[2], o1 = h1 ? a[2] : a[3];
      float r0 = m0 + __shfl_xor(o0, 1, 64);
      float r1 = m1 + __shfl_xor(o1, 1, 64);
      const bool h2 = lane & 2;
      float mm = h2 ? r1 : r0, oo = h2 ? r0 : r1;
      float r = mm + __shfl_xor(oo, 2, 64);
      r += __shfl_xor(r, 4, 64);
      r += __shfl_xor(r, 8, 64);
      r += __shfl_xor(r, 16, 64);
      r += __shfl_xor(r, 32, 64);
      if (lane < QT) s_sc[lane][t] = -2.f * r;
    }
  }
  __syncthreads();

  // ---- softmax: waves 0..3 handle row = wave; waves 4..7 wait ----
  if (wave < QT) {
    const int r = wave;
    float x[4];
    #pragma unroll
    for (int i = 0; i < 4; ++i) x[i] = s_sc[r][lane + 64 * i];
    float m = fmaxf(fmaxf(x[0], x[1]), fmaxf(x[2], x[3]));
    #pragma unroll
    for (int off = 32; off >= 1; off >>= 1) m = fmaxf(m, __shfl_xor(m, off, 64));
    const float L2E = 1.4426950408889634f;
    float ssum = 0.f;
    #pragma unroll
    for (int i = 0; i < 4; ++i) { x[i] = __builtin_amdgcn_exp2f((x[i] - m) * L2E); ssum += x[i]; }
    #pragma unroll
    for (int off = 32; off >= 1; off >>= 1) ssum += __shfl_xor(ssum, off, 64);
    float inv = 1.f / ssum;
    float* oe = out_e + (size_t)(b * TD + q0 + r) * TE;
    #pragma unroll
    for (int i = 0; i < 4; ++i) {
      float e = x[i] * inv;
      s_sc[r][lane + 64 * i] = e;
      oe[lane + 64 * i] = e;
    }
  }
  __syncthreads();

  // ---- context: c[q][f] = sum_t e[q][t]*enc[b][t][f]; thread owns f = tid ----
  float c[QT] = {0.f, 0.f, 0.f, 0.f};
  const float* eb = enc + (size_t)b * TE * DE + tid;
  for (int t = 0; t < TE; t += 4) {
    float ev[QT][4];
    #pragma unroll
    for (int q = 0; q < QT; ++q) *(float4*)ev[q] = *(const float4*)&s_sc[q][t];
    #pragma unroll
    for (int u = 0; u < 4; ++u) {
      float e0 = eb[(size_t)(t + u) * DE];
      #pragma unroll
      for (int q = 0; q < QT; ++q) c[q] = fmaf(ev[q][u], e0, c[q]);
    }
  }
  #pragma unroll
  for (int q = 0; q < QT; ++q)
    out_c[(size_t)(b * TD + q0 + q) * DE + tid] = c[q];
}

extern "C" void kernel_launch(void* const* d_in, const int* in_sizes, int n_in,
                              void* d_out, int out_size, void* d_ws, size_t ws_size,
                              hipStream_t stream) {
  const float* enc = (const float*)d_in[0];
  const float* dec = (const float*)d_in[1];
  const float* Wa  = (const float*)d_in[2];
  const float* Ua  = (const float*)d_in[3];
  const float* Va  = (const float*)d_in[4];
  float* out_c = (float*)d_out;
  float* out_e = out_c + (size_t)NB * TD * DE;         // c first, then e
  float* ws = (float*)d_ws;                            // Ws*K2: 2048x512 f32 (4 MB)
  float* uh = ws + (size_t)NB * TE * DE;               // Uh*K2: 2048x512 f32 (4 MB)

  gemm2<<<dim3(DE / 64, (NB * TE) / 128, 2), dim3(256), 0, stream>>>(
      enc, Wa, ws, dec, Ua, uh);
  attn<<<dim3(NB * (TD / QT)), dim3(512), 0, stream>>>(
      ws, uh, enc, Va, out_c, out_e);
}

// Round 2
// 90.990 us; speedup vs baseline: 1.4153x; 1.1594x over previous
//
#include <hip/hip_runtime.h>

#define NB 8
#define TE 256
#define TD 256
#define DE 512
#define QT 4

// K2 = 2*log2(e): exp2(K2*x) = e^{2x}; tanh(x) = 1 - 2/(e^{2x}+1).
// gemm2 stores exp2(K2*acc) so attn never touches the transcendental pipe for
// inputs: scores come from ew*eu products only.
#define K2SCALE 2.8853900817779268f

// ------- GEMM + exp2 epilogue: C = exp2(K2 * A@W), f32, M=2048 N=K=512 --------
// BM=128 BN=64 BK=16, 512 threads (2 waves/SIMD for latency hiding), 4x4 micro.
// grid = (8, 16, 2)
__global__ __launch_bounds__(512) void gemm2(
    const float* __restrict__ A0, const float* __restrict__ W0, float* __restrict__ C0,
    const float* __restrict__ A1, const float* __restrict__ W1, float* __restrict__ C1)
{
  constexpr int N = DE;        // 512
  constexpr int K = DE;        // 512
  constexpr int BM = 128, BN = 64, BK = 16;
  constexpr int BMp = BM + 4;  // pad: LDS writes 4-way -> 2-way (free)
  const float* A = blockIdx.z ? A1 : A0;
  const float* W = blockIdx.z ? W1 : W0;
  float*       C = blockIdx.z ? C1 : C0;
  const int tid = threadIdx.x;
  const int m0 = blockIdx.y * BM;
  const int n0 = blockIdx.x * BN;
  __shared__ __align__(16) float As[BK][BMp];  // transposed: As[k][m]
  __shared__ __align__(16) float Bs[BK][BN];
  const int am = tid >> 2, ak = (tid & 3) * 4;   // A: row am, 4 k's
  const int bk = tid >> 5, bn = (tid & 31) * 2;  // B: row bk, 2 n's
  const int ty = tid >> 4, tx = tid & 15;        // micro-tile owner (4x4)
  float acc[4][4];
  #pragma unroll
  for (int i = 0; i < 4; ++i)
    #pragma unroll
    for (int j = 0; j < 4; ++j) acc[i][j] = 0.f;

  for (int k0 = 0; k0 < K; k0 += BK) {
    float4 av = *(const float4*)(A + (size_t)(m0 + am) * K + k0 + ak);
    float2 bv = *(const float2*)(W + (size_t)(k0 + bk) * N + n0 + bn);
    __syncthreads();   // previous compute done before LDS overwrite
    As[ak + 0][am] = av.x; As[ak + 1][am] = av.y;
    As[ak + 2][am] = av.z; As[ak + 3][am] = av.w;
    *(float2*)&Bs[bk][bn] = bv;
    __syncthreads();
    #pragma unroll
    for (int k = 0; k < BK; ++k) {
      float4 a = *(const float4*)&As[k][ty * 4];
      float4 b = *(const float4*)&Bs[k][tx * 4];
      float aa[4] = {a.x, a.y, a.z, a.w};
      float bb[4] = {b.x, b.y, b.z, b.w};
      #pragma unroll
      for (int i = 0; i < 4; ++i)
        #pragma unroll
        for (int j = 0; j < 4; ++j)
          acc[i][j] = fmaf(aa[i], bb[j], acc[i][j]);
    }
  }
  #pragma unroll
  for (int i = 0; i < 4; ++i) {
    float4 o = {__builtin_amdgcn_exp2f(acc[i][0] * K2SCALE),
                __builtin_amdgcn_exp2f(acc[i][1] * K2SCALE),
                __builtin_amdgcn_exp2f(acc[i][2] * K2SCALE),
                __builtin_amdgcn_exp2f(acc[i][3] * K2SCALE)};
    *(float4*)(C + (size_t)(m0 + ty * 4 + i) * N + n0 + tx * 4) = o;
  }
}

// ---------------- fused scores + softmax + context -----------------------------
// block = 512 thr (8 waves), handles (b, q-tile of QT=4). grid = 8*64 = 512.
// ws/uh hold ew = e^{2Ws}, eu = e^{2Uh}. Score (up to softmax-invariant const):
//   s[q,t] = -2 * sum_f v[f] / (ew[t,f]*eu[q,f] + 1)
// 4-way rcp combining: v0/A+v1/B+v2/C+v3/D with one rcp per quad
// (denominators >= 1, products <= ~e^40: safe in f32).
__global__ __launch_bounds__(512) void attn(
    const float* __restrict__ ws, const float* __restrict__ uh,
    const float* __restrict__ enc, const float* __restrict__ va,
    float* __restrict__ out_c, float* __restrict__ out_e)
{
  const int tid  = threadIdx.x;
  const int wave = tid >> 6;
  const int lane = tid & 63;
  const int b  = blockIdx.x >> 6;          // TD/QT = 64 tiles per batch
  const int q0 = (blockIdx.x & 63) * QT;
  __shared__ float s_sc[QT][TE];           // 4 KB
  const int fbase = lane * 8;              // lane owns 8 contiguous f

  float4 v0 = *(const float4*)(va + fbase);
  float4 v1 = *(const float4*)(va + fbase + 4);
  float v[8] = {v0.x, v0.y, v0.z, v0.w, v1.x, v1.y, v1.z, v1.w};

  float eu[QT][8];
  #pragma unroll
  for (int q = 0; q < QT; ++q) {
    const float* up = uh + (size_t)(b * TD + q0 + q) * DE + fbase;
    float4 u0 = *(const float4*)(up);
    float4 u1 = *(const float4*)(up + 4);
    eu[q][0] = u0.x; eu[q][1] = u0.y; eu[q][2] = u0.z; eu[q][3] = u0.w;
    eu[q][4] = u1.x; eu[q][5] = u1.y; eu[q][6] = u1.z; eu[q][7] = u1.w;
  }

  // ---- scores: wave owns t in [wave*32, wave*32+32), 1-deep prefetch on ws ----
  const int t0 = wave * 32;
  const float* wp = ws + (size_t)(b * TE + t0) * DE + fbase;
  float4 w0 = *(const float4*)(wp);
  float4 w1 = *(const float4*)(wp + 4);
  for (int t = t0; t < t0 + 32; ++t) {
    float cw[8] = {w0.x, w0.y, w0.z, w0.w, w1.x, w1.y, w1.z, w1.w};
    // prefetch next row; last iteration reads one row past (lands in uh[0],
    // still inside the same workspace allocation) and is unused.
    wp += DE;
    w0 = *(const float4*)(wp);
    w1 = *(const float4*)(wp + 4);
    float a[QT];
    #pragma unroll
    for (int q = 0; q < QT; ++q) {
      float A0 = fmaf(cw[0], eu[q][0], 1.f);
      float A1 = fmaf(cw[1], eu[q][1], 1.f);
      float A2 = fmaf(cw[2], eu[q][2], 1.f);
      float A3 = fmaf(cw[3], eu[q][3], 1.f);
      float B0 = fmaf(cw[4], eu[q][4], 1.f);
      float B1 = fmaf(cw[5], eu[q][5], 1.f);
      float B2 = fmaf(cw[6], eu[q][6], 1.f);
      float B3 = fmaf(cw[7], eu[q][7], 1.f);
      // quad 1: v0/A0 + v1/A1 + v2/A2 + v3/A3
      float n1 = fmaf(v[1], A0, v[0] * A1);
      float d1 = A0 * A1;
      float n2 = fmaf(v[3], A2, v[2] * A3);
      float d2 = A2 * A3;
      float N1 = fmaf(n2, d1, n1 * d2);
      float D1 = d1 * d2;
      // quad 2: v4/B0 + v5/B1 + v6/B2 + v7/B3
      float n3 = fmaf(v[5], B0, v[4] * B1);
      float d3 = B0 * B1;
      float n4 = fmaf(v[7], B2, v[6] * B3);
      float d4 = B2 * B3;
      float N2 = fmaf(n4, d3, n3 * d4);
      float D2 = d3 * d4;
      float s = N1 * __builtin_amdgcn_rcpf(D1);
      a[q] = fmaf(N2, __builtin_amdgcn_rcpf(D2), s);
    }
    // value-halving butterfly: 4 partials over 64 lanes -> lane l holds q=(l&3)
    {
      const bool h1 = lane & 1;
      float m0 = h1 ? a[1] : a[0], o0 = h1 ? a[0] : a[1];
      float m1 = h1 ? a[3] : a[2], o1 = h1 ? a[2] : a[3];
      float r0 = m0 + __shfl_xor(o0, 1, 64);
      float r1 = m1 + __shfl_xor(o1, 1, 64);
      const bool h2 = lane & 2;
      float mm = h2 ? r1 : r0, oo = h2 ? r0 : r1;
      float r = mm + __shfl_xor(oo, 2, 64);
      r += __shfl_xor(r, 4, 64);
      r += __shfl_xor(r, 8, 64);
      r += __shfl_xor(r, 16, 64);
      r += __shfl_xor(r, 32, 64);
      if (lane < QT) s_sc[lane][t] = -2.f * r;
    }
  }
  __syncthreads();

  // ---- softmax: waves 0..3 handle row = wave; waves 4..7 wait ----
  if (wave < QT) {
    const int r = wave;
    float x[4];
    #pragma unroll
    for (int i = 0; i < 4; ++i) x[i] = s_sc[r][lane + 64 * i];
    float m = fmaxf(fmaxf(x[0], x[1]), fmaxf(x[2], x[3]));
    #pragma unroll
    for (int off = 32; off >= 1; off >>= 1) m = fmaxf(m, __shfl_xor(m, off, 64));
    const float L2E = 1.4426950408889634f;
    float ssum = 0.f;
    #pragma unroll
    for (int i = 0; i < 4; ++i) { x[i] = __builtin_amdgcn_exp2f((x[i] - m) * L2E); ssum += x[i]; }
    #pragma unroll
    for (int off = 32; off >= 1; off >>= 1) ssum += __shfl_xor(ssum, off, 64);
    float inv = 1.f / ssum;
    float* oe = out_e + (size_t)(b * TD + q0 + r) * TE;
    #pragma unroll
    for (int i = 0; i < 4; ++i) {
      float e = x[i] * inv;
      s_sc[r][lane + 64 * i] = e;
      oe[lane + 64 * i] = e;
    }
  }
  __syncthreads();

  // ---- context: c[q][f] = sum_t e[q][t]*enc[b][t][f]; thread owns f = tid ----
  float c[QT] = {0.f, 0.f, 0.f, 0.f};
  const float* eb = enc + (size_t)b * TE * DE + tid;
  for (int t = 0; t < TE; t += 4) {
    float ev[QT][4];
    #pragma unroll
    for (int q = 0; q < QT; ++q) *(float4*)ev[q] = *(const float4*)&s_sc[q][t];
    #pragma unroll
    for (int u = 0; u < 4; ++u) {
      float e0 = eb[(size_t)(t + u) * DE];
      #pragma unroll
      for (int q = 0; q < QT; ++q) c[q] = fmaf(ev[q][u], e0, c[q]);
    }
  }
  #pragma unroll
  for (int q = 0; q < QT; ++q)
    out_c[(size_t)(b * TD + q0 + q) * DE + tid] = c[q];
}

extern "C" void kernel_launch(void* const* d_in, const int* in_sizes, int n_in,
                              void* d_out, int out_size, void* d_ws, size_t ws_size,
                              hipStream_t stream) {
  const float* enc = (const float*)d_in[0];
  const float* dec = (const float*)d_in[1];
  const float* Wa  = (const float*)d_in[2];
  const float* Ua  = (const float*)d_in[3];
  const float* Va  = (const float*)d_in[4];
  float* out_c = (float*)d_out;
  float* out_e = out_c + (size_t)NB * TD * DE;         // c first, then e
  float* ws = (float*)d_ws;                            // ew = e^{2Ws}: 4 MB
  float* uh = ws + (size_t)NB * TE * DE;               // eu = e^{2Uh}: 4 MB

  gemm2<<<dim3(DE / 64, (NB * TE) / 128, 2), dim3(512), 0, stream>>>(
      enc, Wa, ws, dec, Ua, uh);
  attn<<<dim3(NB * (TD / QT)), dim3(512), 0, stream>>>(
      ws, uh, enc, Va, out_c, out_e);
}

// Round 3
// 80.987 us; speedup vs baseline: 1.5901x; 1.1235x over previous
//
#include <hip/hip_runtime.h>

#define NB 8
#define TE 256
#define TD 256
#define DE 512
#define QT 4

// K2 = 2*log2(e): exp2(K2*x) = e^{2x}; tanh(x) = 1 - 2/(e^{2x}+1).
// gemm2 stores exp2(K2*acc) so attn never touches the transcendental pipe.
#define K2SCALE 2.8853900817779268f

// ------- GEMM + exp2 epilogue: C = exp2(K2 * A@W), f32, M=2048 N=K=512 --------
// BM=128 BN=64 BK=16, 512 threads, 4x4 micro, DOUBLE-BUFFERED LDS (one barrier
// per K-step; next tile's global loads issued before current compute so their
// latency hides under the FMAs). grid = (8, 16, 2)
__global__ __launch_bounds__(512) void gemm2(
    const float* __restrict__ A0, const float* __restrict__ W0, float* __restrict__ C0,
    const float* __restrict__ A1, const float* __restrict__ W1, float* __restrict__ C1)
{
  constexpr int N = DE;        // 512
  constexpr int K = DE;        // 512
  constexpr int BM = 128, BN = 64, BK = 16;
  constexpr int BMp = BM + 4;  // pad LDS writes
  constexpr int NS = K / BK;   // 32 steps
  const float* A = blockIdx.z ? A1 : A0;
  const float* W = blockIdx.z ? W1 : W0;
  float*       C = blockIdx.z ? C1 : C0;
  const int tid = threadIdx.x;
  const int m0 = blockIdx.y * BM;
  const int n0 = blockIdx.x * BN;
  __shared__ __align__(16) float As[2][BK][BMp];
  __shared__ __align__(16) float Bs[2][BK][BN];
  const int am = tid >> 2, ak = (tid & 3) * 4;   // A: row am, 4 k's
  const int bk = tid >> 5, bn = (tid & 31) * 2;  // B: row bk, 2 n's
  const int ty = tid >> 4, tx = tid & 15;        // micro-tile owner (4x4)

  // prologue: stage tile 0
  float4 av = *(const float4*)(A + (size_t)(m0 + am) * K + ak);
  float2 bv = *(const float2*)(W + (size_t)bk * N + n0 + bn);
  As[0][ak + 0][am] = av.x; As[0][ak + 1][am] = av.y;
  As[0][ak + 2][am] = av.z; As[0][ak + 3][am] = av.w;
  *(float2*)&Bs[0][bk][bn] = bv;
  __syncthreads();

  float acc[4][4];
  #pragma unroll
  for (int i = 0; i < 4; ++i)
    #pragma unroll
    for (int j = 0; j < 4; ++j) acc[i][j] = 0.f;

  for (int s = 0; s < NS; ++s) {
    const int cur = s & 1;
    if (s + 1 < NS) {            // issue next-tile loads; latency hides under FMAs
      const int k0 = (s + 1) * BK;
      av = *(const float4*)(A + (size_t)(m0 + am) * K + k0 + ak);
      bv = *(const float2*)(W + (size_t)(k0 + bk) * N + n0 + bn);
    }
    #pragma unroll
    for (int k = 0; k < BK; ++k) {
      float4 a = *(const float4*)&As[cur][k][ty * 4];
      float4 b = *(const float4*)&Bs[cur][k][tx * 4];
      float aa[4] = {a.x, a.y, a.z, a.w};
      float bb[4] = {b.x, b.y, b.z, b.w};
      #pragma unroll
      for (int i = 0; i < 4; ++i)
        #pragma unroll
        for (int j = 0; j < 4; ++j)
          acc[i][j] = fmaf(aa[i], bb[j], acc[i][j]);
    }
    if (s + 1 < NS) {            // write OTHER buffer; single barrier per step
      const int nxt = cur ^ 1;
      As[nxt][ak + 0][am] = av.x; As[nxt][ak + 1][am] = av.y;
      As[nxt][ak + 2][am] = av.z; As[nxt][ak + 3][am] = av.w;
      *(float2*)&Bs[nxt][bk][bn] = bv;
      __syncthreads();
    }
  }
  #pragma unroll
  for (int i = 0; i < 4; ++i) {
    float4 o = {__builtin_amdgcn_exp2f(acc[i][0] * K2SCALE),
                __builtin_amdgcn_exp2f(acc[i][1] * K2SCALE),
                __builtin_amdgcn_exp2f(acc[i][2] * K2SCALE),
                __builtin_amdgcn_exp2f(acc[i][3] * K2SCALE)};
    *(float4*)(C + (size_t)(m0 + ty * 4 + i) * N + n0 + tx * 4) = o;
  }
}

// ---------------- fused scores + softmax + context -----------------------------
// block = 512 thr (8 waves), handles (b, q-tile of QT=4). grid = 8*64 = 512.
// ws/uh hold ew = e^{2Ws}, eu = e^{2Uh}. Score (up to softmax-invariant const):
//   s[q,t] = -2 * sum_f v[f] / (ew[t,f]*eu[q,f] + 1)
// 4-way rcp combining (denominators >= 1, products <= ~e^40: safe in f32).
// Context phase: thread owns float4 of f + one of 4 t-ranges -> float4 loads,
// 16 fma/load; partial c's reduced through LDS.
__global__ __launch_bounds__(512) void attn(
    const float* __restrict__ ws, const float* __restrict__ uh,
    const float* __restrict__ enc, const float* __restrict__ va,
    float* __restrict__ out_c, float* __restrict__ out_e)
{
  const int tid  = threadIdx.x;
  const int wave = tid >> 6;
  const int lane = tid & 63;
  const int b  = blockIdx.x >> 6;          // TD/QT = 64 tiles per batch
  const int q0 = (blockIdx.x & 63) * QT;
  __shared__ float s_sc[QT][TE];           // 4 KB
  __shared__ float red[3][QT][DE];         // 24 KB, context partials
  const int fbase = lane * 8;              // lane owns 8 contiguous f

  float4 v0 = *(const float4*)(va + fbase);
  float4 v1 = *(const float4*)(va + fbase + 4);
  float v[8] = {v0.x, v0.y, v0.z, v0.w, v1.x, v1.y, v1.z, v1.w};

  float eu[QT][8];
  #pragma unroll
  for (int q = 0; q < QT; ++q) {
    const float* up = uh + (size_t)(b * TD + q0 + q) * DE + fbase;
    float4 u0 = *(const float4*)(up);
    float4 u1 = *(const float4*)(up + 4);
    eu[q][0] = u0.x; eu[q][1] = u0.y; eu[q][2] = u0.z; eu[q][3] = u0.w;
    eu[q][4] = u1.x; eu[q][5] = u1.y; eu[q][6] = u1.z; eu[q][7] = u1.w;
  }

  // ---- scores: wave owns t in [wave*32, wave*32+32), 1-deep prefetch on ws ----
  const int t0 = wave * 32;
  const float* wp = ws + (size_t)(b * TE + t0) * DE + fbase;
  float4 w0 = *(const float4*)(wp);
  float4 w1 = *(const float4*)(wp + 4);
  for (int t = t0; t < t0 + 32; ++t) {
    float cw[8] = {w0.x, w0.y, w0.z, w0.w, w1.x, w1.y, w1.z, w1.w};
    // prefetch next row; last iteration reads one row past (lands in uh[0],
    // still inside the same workspace allocation) and is unused.
    wp += DE;
    w0 = *(const float4*)(wp);
    w1 = *(const float4*)(wp + 4);
    float a[QT];
    #pragma unroll
    for (int q = 0; q < QT; ++q) {
      float A0 = fmaf(cw[0], eu[q][0], 1.f);
      float A1 = fmaf(cw[1], eu[q][1], 1.f);
      float A2 = fmaf(cw[2], eu[q][2], 1.f);
      float A3 = fmaf(cw[3], eu[q][3], 1.f);
      float B0 = fmaf(cw[4], eu[q][4], 1.f);
      float B1 = fmaf(cw[5], eu[q][5], 1.f);
      float B2 = fmaf(cw[6], eu[q][6], 1.f);
      float B3 = fmaf(cw[7], eu[q][7], 1.f);
      float n1 = fmaf(v[1], A0, v[0] * A1);
      float d1 = A0 * A1;
      float n2 = fmaf(v[3], A2, v[2] * A3);
      float d2 = A2 * A3;
      float N1 = fmaf(n2, d1, n1 * d2);
      float D1 = d1 * d2;
      float n3 = fmaf(v[5], B0, v[4] * B1);
      float d3 = B0 * B1;
      float n4 = fmaf(v[7], B2, v[6] * B3);
      float d4 = B2 * B3;
      float N2 = fmaf(n4, d3, n3 * d4);
      float D2 = d3 * d4;
      float s = N1 * __builtin_amdgcn_rcpf(D1);
      a[q] = fmaf(N2, __builtin_amdgcn_rcpf(D2), s);
    }
    // value-halving butterfly: 4 partials over 64 lanes -> lane l holds q=(l&3)
    {
      const bool h1 = lane & 1;
      float m0 = h1 ? a[1] : a[0], o0 = h1 ? a[0] : a[1];
      float m1 = h1 ? a[3] : a[2], o1 = h1 ? a[2] : a[3];
      float r0 = m0 + __shfl_xor(o0, 1, 64);
      float r1 = m1 + __shfl_xor(o1, 1, 64);
      const bool h2 = lane & 2;
      float mm = h2 ? r1 : r0, oo = h2 ? r0 : r1;
      float r = mm + __shfl_xor(oo, 2, 64);
      r += __shfl_xor(r, 4, 64);
      r += __shfl_xor(r, 8, 64);
      r += __shfl_xor(r, 16, 64);
      r += __shfl_xor(r, 32, 64);
      if (lane < QT) s_sc[lane][t] = -2.f * r;
    }
  }
  __syncthreads();

  // ---- softmax: waves 0..3 handle row = wave; waves 4..7 wait ----
  if (wave < QT) {
    const int r = wave;
    float x[4];
    #pragma unroll
    for (int i = 0; i < 4; ++i) x[i] = s_sc[r][lane + 64 * i];
    float m = fmaxf(fmaxf(x[0], x[1]), fmaxf(x[2], x[3]));
    #pragma unroll
    for (int off = 32; off >= 1; off >>= 1) m = fmaxf(m, __shfl_xor(m, off, 64));
    const float L2E = 1.4426950408889634f;
    float ssum = 0.f;
    #pragma unroll
    for (int i = 0; i < 4; ++i) { x[i] = __builtin_amdgcn_exp2f((x[i] - m) * L2E); ssum += x[i]; }
    #pragma unroll
    for (int off = 32; off >= 1; off >>= 1) ssum += __shfl_xor(ssum, off, 64);
    float inv = 1.f / ssum;
    float* oe = out_e + (size_t)(b * TD + q0 + r) * TE;
    #pragma unroll
    for (int i = 0; i < 4; ++i) {
      float e = x[i] * inv;
      s_sc[r][lane + 64 * i] = e;
      oe[lane + 64 * i] = e;
    }
  }
  __syncthreads();

  // ---- context: c[q][f4..f4+3] = sum_t e[q][t]*enc[b][t][f4..f4+3] ----
  // thread owns f4 = (tid&127)*4 and t-range (tid>>7)*64..+63; LDS reduce.
  {
    const int fgrp = tid >> 7;           // 0..3
    const int f4   = (tid & 127) * 4;
    float4 c[QT];
    #pragma unroll
    for (int q = 0; q < QT; ++q) c[q] = make_float4(0.f, 0.f, 0.f, 0.f);
    const float* eb = enc + (size_t)b * TE * DE + f4;
    const int tb = fgrp * 64;
    #pragma unroll 4
    for (int t = tb; t < tb + 64; ++t) {
      float4 ee = *(const float4*)(eb + (size_t)t * DE);
      #pragma unroll
      for (int q = 0; q < QT; ++q) {
        float w = s_sc[q][t];
        c[q].x = fmaf(w, ee.x, c[q].x);
        c[q].y = fmaf(w, ee.y, c[q].y);
        c[q].z = fmaf(w, ee.z, c[q].z);
        c[q].w = fmaf(w, ee.w, c[q].w);
      }
    }
    if (fgrp > 0) {
      #pragma unroll
      for (int q = 0; q < QT; ++q) *(float4*)&red[fgrp - 1][q][f4] = c[q];
    }
    __syncthreads();
    if (fgrp == 0) {
      #pragma unroll
      for (int q = 0; q < QT; ++q) {
        float4 r1 = *(const float4*)&red[0][q][f4];
        float4 r2 = *(const float4*)&red[1][q][f4];
        float4 r3 = *(const float4*)&red[2][q][f4];
        c[q].x += (r1.x + r2.x) + r3.x;
        c[q].y += (r1.y + r2.y) + r3.y;
        c[q].z += (r1.z + r2.z) + r3.z;
        c[q].w += (r1.w + r2.w) + r3.w;
        *(float4*)(out_c + (size_t)(b * TD + q0 + q) * DE + f4) = c[q];
      }
    }
  }
}

extern "C" void kernel_launch(void* const* d_in, const int* in_sizes, int n_in,
                              void* d_out, int out_size, void* d_ws, size_t ws_size,
                              hipStream_t stream) {
  const float* enc = (const float*)d_in[0];
  const float* dec = (const float*)d_in[1];
  const float* Wa  = (const float*)d_in[2];
  const float* Ua  = (const float*)d_in[3];
  const float* Va  = (const float*)d_in[4];
  float* out_c = (float*)d_out;
  float* out_e = out_c + (size_t)NB * TD * DE;         // c first, then e
  float* ws = (float*)d_ws;                            // ew = e^{2Ws}: 4 MB
  float* uh = ws + (size_t)NB * TE * DE;               // eu = e^{2Uh}: 4 MB

  gemm2<<<dim3(DE / 64, (NB * TE) / 128, 2), dim3(512), 0, stream>>>(
      enc, Wa, ws, dec, Ua, uh);
  attn<<<dim3(NB * (TD / QT)), dim3(512), 0, stream>>>(
      ws, uh, enc, Va, out_c, out_e);
}

// Round 4
// 76.969 us; speedup vs baseline: 1.6731x; 1.0522x over previous
//
#include <hip/hip_runtime.h>

#define NB 8
#define TE 256
#define TD 256
#define DE 512
#define QT 4

// K2 = 2*log2(e): exp2(K2*x) = e^{2x}; tanh(x) = 1 - 2/(e^{2x}+1).
#define K2SCALE 2.8853900817779268f

typedef short bf16x8 __attribute__((ext_vector_type(8)));           // 8 bf16 (4 VGPR)
typedef float f32x4 __attribute__((ext_vector_type(4)));            // MFMA acc
typedef unsigned short u16x8 __attribute__((ext_vector_type(8)));   // 16 B staging

// round-to-nearest-even f32 -> bf16
static __device__ __forceinline__ unsigned short f2bf(float x) {
  unsigned int u = __float_as_uint(x);
  u += 0x7fffu + ((u >> 16) & 1u);
  return (unsigned short)(u >> 16);
}

// ---- convA: split f32 A-matrices [2048x512] into hi/lo bf16 (elementwise) ----
// grid (512, 1, 2), 256 thr; thread handles 8 elements.
__global__ __launch_bounds__(256) void convA(
    const float* __restrict__ s0, unsigned short* __restrict__ h0, unsigned short* __restrict__ l0,
    const float* __restrict__ s1, unsigned short* __restrict__ h1, unsigned short* __restrict__ l1)
{
  const float* s = blockIdx.z ? s1 : s0;
  unsigned short* H = blockIdx.z ? h1 : h0;
  unsigned short* L = blockIdx.z ? l1 : l0;
  size_t base = ((size_t)blockIdx.x * 256 + threadIdx.x) * 8;
  float4 x0 = *(const float4*)(s + base);
  float4 x1 = *(const float4*)(s + base + 4);
  float xs[8] = {x0.x, x0.y, x0.z, x0.w, x1.x, x1.y, x1.z, x1.w};
  u16x8 h, l;
  #pragma unroll
  for (int j = 0; j < 8; ++j) {
    unsigned short hh = f2bf(xs[j]);
    float hf = __uint_as_float((unsigned int)hh << 16);
    h[j] = hh;
    l[j] = f2bf(xs[j] - hf);
  }
  *(u16x8*)(H + base) = h;
  *(u16x8*)(L + base) = l;
}

// ---- convB: W [512x512] f32 -> TRANSPOSED hi/lo bf16 BT[n][k] (32x32 tiles) ----
// grid (16, 16, 2), 256 thr.
__global__ __launch_bounds__(256) void convB(
    const float* __restrict__ w0, unsigned short* __restrict__ h0, unsigned short* __restrict__ l0,
    const float* __restrict__ w1, unsigned short* __restrict__ h1, unsigned short* __restrict__ l1)
{
  const float* W = blockIdx.z ? w1 : w0;
  unsigned short* H = blockIdx.z ? h1 : h0;
  unsigned short* L = blockIdx.z ? l1 : l0;
  __shared__ unsigned short sh[32][33], sl[32][33];
  const int t = threadIdx.x;
  const int k0 = blockIdx.y * 32, n0 = blockIdx.x * 32;
  const int r = t >> 3, c = (t & 7) * 4;
  float4 x = *(const float4*)(W + (size_t)(k0 + r) * DE + n0 + c);
  float xs[4] = {x.x, x.y, x.z, x.w};
  #pragma unroll
  for (int j = 0; j < 4; ++j) {
    unsigned short hh = f2bf(xs[j]);
    float hf = __uint_as_float((unsigned int)hh << 16);
    sh[r][c + j] = hh;
    sl[r][c + j] = f2bf(xs[j] - hf);
  }
  __syncthreads();
  ushort4 oh, ol;
  oh.x = sh[c + 0][r]; oh.y = sh[c + 1][r]; oh.z = sh[c + 2][r]; oh.w = sh[c + 3][r];
  ol.x = sl[c + 0][r]; ol.y = sl[c + 1][r]; ol.z = sl[c + 2][r]; ol.w = sl[c + 3][r];
  *(ushort4*)(H + (size_t)(n0 + r) * DE + k0 + c) = oh;
  *(ushort4*)(L + (size_t)(n0 + r) * DE + k0 + c) = ol;
}

// ---- gemm_mfma: C = exp2(K2 * A@B) via split-bf16 3-term MFMA ------------------
// A: [2048x512] as AH/AL bf16 [m][k]; B: transposed BH/BL bf16 [n][k].
// acc = AH*BH + (AL*BH + AH*BL)   (lo*lo dropped, ~2^-17 relative: negligible)
// BM=128 BN=64 KT=32, 256 thr (4 waves, 2x2), wave-tile 64x32 = 4x2 16x16 tiles.
// grid (8, 16, 2). C/D layout (HW-verified): col=lane&15, row=(lane>>4)*4+j.
// A/B frag k-map is a free bijection as long as A and B use the SAME map.
__global__ __launch_bounds__(256) void gemm_mfma(
    const unsigned short* __restrict__ AH0, const unsigned short* __restrict__ AL0,
    const unsigned short* __restrict__ BH0, const unsigned short* __restrict__ BL0,
    float* __restrict__ C0,
    const unsigned short* __restrict__ AH1, const unsigned short* __restrict__ AL1,
    const unsigned short* __restrict__ BH1, const unsigned short* __restrict__ BL1,
    float* __restrict__ C1)
{
  const unsigned short* AH = blockIdx.z ? AH1 : AH0;
  const unsigned short* AL = blockIdx.z ? AL1 : AL0;
  const unsigned short* BH = blockIdx.z ? BH1 : BH0;
  const unsigned short* BL = blockIdx.z ? BL1 : BL0;
  float*               C  = blockIdx.z ? C1  : C0;
  const int tid  = threadIdx.x;
  const int lane = tid & 63;
  const int wave = tid >> 6;
  const int wm = wave >> 1, wn = wave & 1;
  const int g = lane >> 4, r16 = lane & 15;
  const int m0 = blockIdx.y * 128, n0 = blockIdx.x * 64;
  // LDS: rows padded to 40 ushorts (80 B, 16B-aligned) for bank spread
  __shared__ __align__(16) unsigned short Ah[128][40], Al[128][40];
  __shared__ __align__(16) unsigned short Bh[64][40],  Bl[64][40];
  const int arow = tid >> 2;            // 0..63 (+64 for second chunk)
  const int apart = (tid & 3) * 8;      // 8-elem (16 B) piece of a 32-elem row

  u16x8 pa0, pa1, pla0, pla1, pb, plb;
#define LOADTILE(KT) do {                                                   \
    const size_t ko = (size_t)(KT) * 32 + apart;                            \
    const unsigned short* pa_ = AH + (size_t)(m0 + arow) * 512 + ko;        \
    const unsigned short* pl_ = AL + (size_t)(m0 + arow) * 512 + ko;        \
    const unsigned short* qb_ = BH + (size_t)(n0 + arow) * 512 + ko;        \
    const unsigned short* ql_ = BL + (size_t)(n0 + arow) * 512 + ko;        \
    pa0 = *(const u16x8*)pa_;  pa1 = *(const u16x8*)(pa_ + 64 * 512);       \
    pla0 = *(const u16x8*)pl_; pla1 = *(const u16x8*)(pl_ + 64 * 512);      \
    pb = *(const u16x8*)qb_;   plb = *(const u16x8*)ql_;                    \
  } while (0)

  f32x4 accm[4][2], acce[4][2];
  #pragma unroll
  for (int mt = 0; mt < 4; ++mt)
    #pragma unroll
    for (int nt = 0; nt < 2; ++nt) {
      accm[mt][nt] = (f32x4){0.f, 0.f, 0.f, 0.f};
      acce[mt][nt] = (f32x4){0.f, 0.f, 0.f, 0.f};
    }

  LOADTILE(0);
  for (int kt = 0; kt < 16; ++kt) {
    __syncthreads();                    // previous compute done
    *(u16x8*)&Ah[arow][apart] = pa0;
    *(u16x8*)&Ah[arow + 64][apart] = pa1;
    *(u16x8*)&Al[arow][apart] = pla0;
    *(u16x8*)&Al[arow + 64][apart] = pla1;
    *(u16x8*)&Bh[arow][apart] = pb;
    *(u16x8*)&Bl[arow][apart] = plb;
    __syncthreads();                    // staging visible
    if (kt + 1 < 16) LOADTILE(kt + 1);  // prefetch hides under compute
    bf16x8 ah[4], al[4], bh[2], bl[2];
    #pragma unroll
    for (int mt = 0; mt < 4; ++mt) {
      ah[mt] = *(const bf16x8*)&Ah[wm * 64 + mt * 16 + r16][g * 8];
      al[mt] = *(const bf16x8*)&Al[wm * 64 + mt * 16 + r16][g * 8];
    }
    #pragma unroll
    for (int nt = 0; nt < 2; ++nt) {
      bh[nt] = *(const bf16x8*)&Bh[wn * 32 + nt * 16 + r16][g * 8];
      bl[nt] = *(const bf16x8*)&Bl[wn * 32 + nt * 16 + r16][g * 8];
    }
    #pragma unroll
    for (int mt = 0; mt < 4; ++mt)
      #pragma unroll
      for (int nt = 0; nt < 2; ++nt) {
        accm[mt][nt] = __builtin_amdgcn_mfma_f32_16x16x32_bf16(ah[mt], bh[nt], accm[mt][nt], 0, 0, 0);
        acce[mt][nt] = __builtin_amdgcn_mfma_f32_16x16x32_bf16(al[mt], bh[nt], acce[mt][nt], 0, 0, 0);
        acce[mt][nt] = __builtin_amdgcn_mfma_f32_16x16x32_bf16(ah[mt], bl[nt], acce[mt][nt], 0, 0, 0);
      }
  }
#undef LOADTILE

  #pragma unroll
  for (int mt = 0; mt < 4; ++mt)
    #pragma unroll
    for (int nt = 0; nt < 2; ++nt)
      #pragma unroll
      for (int j = 0; j < 4; ++j) {
        float vsum = accm[mt][nt][j] + acce[mt][nt][j];
        int row = m0 + wm * 64 + mt * 16 + g * 4 + j;
        int col = n0 + wn * 32 + nt * 16 + r16;
        C[(size_t)row * 512 + col] = __builtin_amdgcn_exp2f(vsum * K2SCALE);
      }
}

// ---------------- fused scores + softmax + context (unchanged) -----------------
__global__ __launch_bounds__(512) void attn(
    const float* __restrict__ ws, const float* __restrict__ uh,
    const float* __restrict__ enc, const float* __restrict__ va,
    float* __restrict__ out_c, float* __restrict__ out_e)
{
  const int tid  = threadIdx.x;
  const int wave = tid >> 6;
  const int lane = tid & 63;
  const int b  = blockIdx.x >> 6;          // TD/QT = 64 tiles per batch
  const int q0 = (blockIdx.x & 63) * QT;
  __shared__ float s_sc[QT][TE];           // 4 KB
  __shared__ float red[3][QT][DE];         // 24 KB, context partials
  const int fbase = lane * 8;              // lane owns 8 contiguous f

  float4 v0 = *(const float4*)(va + fbase);
  float4 v1 = *(const float4*)(va + fbase + 4);
  float v[8] = {v0.x, v0.y, v0.z, v0.w, v1.x, v1.y, v1.z, v1.w};

  float eu[QT][8];
  #pragma unroll
  for (int q = 0; q < QT; ++q) {
    const float* up = uh + (size_t)(b * TD + q0 + q) * DE + fbase;
    float4 u0 = *(const float4*)(up);
    float4 u1 = *(const float4*)(up + 4);
    eu[q][0] = u0.x; eu[q][1] = u0.y; eu[q][2] = u0.z; eu[q][3] = u0.w;
    eu[q][4] = u1.x; eu[q][5] = u1.y; eu[q][6] = u1.z; eu[q][7] = u1.w;
  }

  const int t0 = wave * 32;
  const float* wp = ws + (size_t)(b * TE + t0) * DE + fbase;
  float4 w0 = *(const float4*)(wp);
  float4 w1 = *(const float4*)(wp + 4);
  for (int t = t0; t < t0 + 32; ++t) {
    float cw[8] = {w0.x, w0.y, w0.z, w0.w, w1.x, w1.y, w1.z, w1.w};
    wp += DE;
    w0 = *(const float4*)(wp);
    w1 = *(const float4*)(wp + 4);
    float a[QT];
    #pragma unroll
    for (int q = 0; q < QT; ++q) {
      float A0 = fmaf(cw[0], eu[q][0], 1.f);
      float A1 = fmaf(cw[1], eu[q][1], 1.f);
      float A2 = fmaf(cw[2], eu[q][2], 1.f);
      float A3 = fmaf(cw[3], eu[q][3], 1.f);
      float B0 = fmaf(cw[4], eu[q][4], 1.f);
      float B1 = fmaf(cw[5], eu[q][5], 1.f);
      float B2 = fmaf(cw[6], eu[q][6], 1.f);
      float B3 = fmaf(cw[7], eu[q][7], 1.f);
      float n1 = fmaf(v[1], A0, v[0] * A1);
      float d1 = A0 * A1;
      float n2 = fmaf(v[3], A2, v[2] * A3);
      float d2 = A2 * A3;
      float N1 = fmaf(n2, d1, n1 * d2);
      float D1 = d1 * d2;
      float n3 = fmaf(v[5], B0, v[4] * B1);
      float d3 = B0 * B1;
      float n4 = fmaf(v[7], B2, v[6] * B3);
      float d4 = B2 * B3;
      float N2 = fmaf(n4, d3, n3 * d4);
      float D2 = d3 * d4;
      float s = N1 * __builtin_amdgcn_rcpf(D1);
      a[q] = fmaf(N2, __builtin_amdgcn_rcpf(D2), s);
    }
    {
      const bool h1 = lane & 1;
      float m0 = h1 ? a[1] : a[0], o0 = h1 ? a[0] : a[1];
      float m1 = h1 ? a[3] : a[2], o1 = h1 ? a[2] : a[3];
      float r0 = m0 + __shfl_xor(o0, 1, 64);
      float r1 = m1 + __shfl_xor(o1, 1, 64);
      const bool h2 = lane & 2;
      float mm = h2 ? r1 : r0, oo = h2 ? r0 : r1;
      float r = mm + __shfl_xor(oo, 2, 64);
      r += __shfl_xor(r, 4, 64);
      r += __shfl_xor(r, 8, 64);
      r += __shfl_xor(r, 16, 64);
      r += __shfl_xor(r, 32, 64);
      if (lane < QT) s_sc[lane][t] = -2.f * r;
    }
  }
  __syncthreads();

  if (wave < QT) {
    const int r = wave;
    float x[4];
    #pragma unroll
    for (int i = 0; i < 4; ++i) x[i] = s_sc[r][lane + 64 * i];
    float m = fmaxf(fmaxf(x[0], x[1]), fmaxf(x[2], x[3]));
    #pragma unroll
    for (int off = 32; off >= 1; off >>= 1) m = fmaxf(m, __shfl_xor(m, off, 64));
    const float L2E = 1.4426950408889634f;
    float ssum = 0.f;
    #pragma unroll
    for (int i = 0; i < 4; ++i) { x[i] = __builtin_amdgcn_exp2f((x[i] - m) * L2E); ssum += x[i]; }
    #pragma unroll
    for (int off = 32; off >= 1; off >>= 1) ssum += __shfl_xor(ssum, off, 64);
    float inv = 1.f / ssum;
    float* oe = out_e + (size_t)(b * TD + q0 + r) * TE;
    #pragma unroll
    for (int i = 0; i < 4; ++i) {
      float e = x[i] * inv;
      s_sc[r][lane + 64 * i] = e;
      oe[lane + 64 * i] = e;
    }
  }
  __syncthreads();

  {
    const int fgrp = tid >> 7;           // 0..3
    const int f4   = (tid & 127) * 4;
    float4 c[QT];
    #pragma unroll
    for (int q = 0; q < QT; ++q) c[q] = make_float4(0.f, 0.f, 0.f, 0.f);
    const float* eb = enc + (size_t)b * TE * DE + f4;
    const int tb = fgrp * 64;
    #pragma unroll 4
    for (int t = tb; t < tb + 64; ++t) {
      float4 ee = *(const float4*)(eb + (size_t)t * DE);
      #pragma unroll
      for (int q = 0; q < QT; ++q) {
        float w = s_sc[q][t];
        c[q].x = fmaf(w, ee.x, c[q].x);
        c[q].y = fmaf(w, ee.y, c[q].y);
        c[q].z = fmaf(w, ee.z, c[q].z);
        c[q].w = fmaf(w, ee.w, c[q].w);
      }
    }
    if (fgrp > 0) {
      #pragma unroll
      for (int q = 0; q < QT; ++q) *(float4*)&red[fgrp - 1][q][f4] = c[q];
    }
    __syncthreads();
    if (fgrp == 0) {
      #pragma unroll
      for (int q = 0; q < QT; ++q) {
        float4 r1 = *(const float4*)&red[0][q][f4];
        float4 r2 = *(const float4*)&red[1][q][f4];
        float4 r3 = *(const float4*)&red[2][q][f4];
        c[q].x += (r1.x + r2.x) + r3.x;
        c[q].y += (r1.y + r2.y) + r3.y;
        c[q].z += (r1.z + r2.z) + r3.z;
        c[q].w += (r1.w + r2.w) + r3.w;
        *(float4*)(out_c + (size_t)(b * TD + q0 + q) * DE + f4) = c[q];
      }
    }
  }
}

extern "C" void kernel_launch(void* const* d_in, const int* in_sizes, int n_in,
                              void* d_out, int out_size, void* d_ws, size_t ws_size,
                              hipStream_t stream) {
  const float* enc = (const float*)d_in[0];
  const float* dec = (const float*)d_in[1];
  const float* Wa  = (const float*)d_in[2];
  const float* Ua  = (const float*)d_in[3];
  const float* Va  = (const float*)d_in[4];
  float* out_c = (float*)d_out;
  float* out_e = out_c + (size_t)NB * TD * DE;          // c first, then e

  // workspace layout (18 MB):
  float* ws = (float*)d_ws;                             // ew = e^{2Ws}: 4 MB
  float* uh = ws + 1048576;                             // eu = e^{2Uh}: 4 MB
  unsigned short* AHe = (unsigned short*)(uh + 1048576);
  unsigned short* ALe = AHe + 1048576;                  // 2 MB each
  unsigned short* AHd = ALe + 1048576;
  unsigned short* ALd = AHd + 1048576;
  unsigned short* BHw = ALd + 1048576;                  // 0.5 MB each
  unsigned short* BLw = BHw + 262144;
  unsigned short* BHu = BLw + 262144;
  unsigned short* BLu = BHu + 262144;

  convA<<<dim3(512, 1, 2), dim3(256), 0, stream>>>(enc, AHe, ALe, dec, AHd, ALd);
  convB<<<dim3(16, 16, 2), dim3(256), 0, stream>>>(Wa, BHw, BLw, Ua, BHu, BLu);
  gemm_mfma<<<dim3(8, 16, 2), dim3(256), 0, stream>>>(
      AHe, ALe, BHw, BLw, ws, AHd, ALd, BHu, BLu, uh);
  attn<<<dim3(NB * (TD / QT)), dim3(512), 0, stream>>>(
      ws, uh, enc, Va, out_c, out_e);
}

// Round 5
// 72.091 us; speedup vs baseline: 1.7863x; 1.0677x over previous
//
#include <hip/hip_runtime.h>

#define NB 8
#define TE 256
#define TD 256
#define DE 512
#define QT 4

// K2 = 2*log2(e): exp2(K2*x) = e^{2x}; tanh(x) = 1 - 2/(e^{2x}+1).
#define K2SCALE 2.8853900817779268f

typedef short bf16x8 __attribute__((ext_vector_type(8)));           // 8 bf16 (4 VGPR)
typedef float f32x4 __attribute__((ext_vector_type(4)));            // MFMA acc
typedef unsigned short u16x8 __attribute__((ext_vector_type(8)));   // 16 B staging

// round-to-nearest-even f32 -> bf16
static __device__ __forceinline__ unsigned short f2bf(float x) {
  unsigned int u = __float_as_uint(x);
  u += 0x7fffu + ((u >> 16) & 1u);
  return (unsigned short)(u >> 16);
}

// split f32 -> hi (truncated top-16) + lo (rounded residual).
// x = hi + lo + rho, |rho| <= 2^-17 |x|; dropped AL*BL term <= 2^-16|A||B|.
static __device__ __forceinline__ void split8(
    const float4& x0, const float4& x1, u16x8& h, u16x8& l) {
  float xs[8] = {x0.x, x0.y, x0.z, x0.w, x1.x, x1.y, x1.z, x1.w};
  #pragma unroll
  for (int j = 0; j < 8; ++j) {
    unsigned int u = __float_as_uint(xs[j]);
    h[j] = (unsigned short)(u >> 16);
    float hf = __uint_as_float(u & 0xffff0000u);
    l[j] = f2bf(xs[j] - hf);
  }
}

// ---- convB: W [512x512] f32 -> TRANSPOSED hi/lo bf16 BT[n][k] (32x32 tiles) ----
// grid (16, 16, 2), 256 thr.
__global__ __launch_bounds__(256) void convB(
    const float* __restrict__ w0, unsigned short* __restrict__ h0, unsigned short* __restrict__ l0,
    const float* __restrict__ w1, unsigned short* __restrict__ h1, unsigned short* __restrict__ l1)
{
  const float* W = blockIdx.z ? w1 : w0;
  unsigned short* H = blockIdx.z ? h1 : h0;
  unsigned short* L = blockIdx.z ? l1 : l0;
  __shared__ unsigned short sh[32][33], sl[32][33];
  const int t = threadIdx.x;
  const int k0 = blockIdx.y * 32, n0 = blockIdx.x * 32;
  const int r = t >> 3, c = (t & 7) * 4;
  float4 x = *(const float4*)(W + (size_t)(k0 + r) * DE + n0 + c);
  float xs[4] = {x.x, x.y, x.z, x.w};
  #pragma unroll
  for (int j = 0; j < 4; ++j) {
    unsigned short hh = f2bf(xs[j]);
    float hf = __uint_as_float((unsigned int)hh << 16);
    sh[r][c + j] = hh;
    sl[r][c + j] = f2bf(xs[j] - hf);
  }
  __syncthreads();
  ushort4 oh, ol;
  oh.x = sh[c + 0][r]; oh.y = sh[c + 1][r]; oh.z = sh[c + 2][r]; oh.w = sh[c + 3][r];
  ol.x = sl[c + 0][r]; ol.y = sl[c + 1][r]; ol.z = sl[c + 2][r]; ol.w = sl[c + 3][r];
  *(ushort4*)(H + (size_t)(n0 + r) * DE + k0 + c) = oh;
  *(ushort4*)(L + (size_t)(n0 + r) * DE + k0 + c) = ol;
}

// ---- gemm_mfma: C = exp2(K2 * A@B), A f32 split in-register, dbuf LDS ---------
// A: f32 [2048x512] (enc/dec directly); B: transposed BH/BL bf16 [n][k] (convB).
// acc = AH*BH + (AL*BH + AH*BL). BM=128 BN=64 KT=32, 256 thr (4 waves, 2x2),
// wave-tile 64x32 = 4x2 16x16 frags. grid (8, 16, 2). ONE barrier per k-tile.
// C/D layout (HW-verified): col=lane&15, row=(lane>>4)*4+j.
__global__ __launch_bounds__(256) void gemm_mfma(
    const float* __restrict__ A0,
    const unsigned short* __restrict__ BH0, const unsigned short* __restrict__ BL0,
    float* __restrict__ C0,
    const float* __restrict__ A1,
    const unsigned short* __restrict__ BH1, const unsigned short* __restrict__ BL1,
    float* __restrict__ C1)
{
  const float*          A  = blockIdx.z ? A1  : A0;
  const unsigned short* BH = blockIdx.z ? BH1 : BH0;
  const unsigned short* BL = blockIdx.z ? BL1 : BL0;
  float*                C  = blockIdx.z ? C1  : C0;
  const int tid  = threadIdx.x;
  const int lane = tid & 63;
  const int wave = tid >> 6;
  const int wm = wave >> 1, wn = wave & 1;
  const int g = lane >> 4, r16 = lane & 15;
  const int m0 = blockIdx.y * 128, n0 = blockIdx.x * 64;
  // double-buffered LDS, rows padded to 40 ushorts (80 B)
  __shared__ __align__(16) unsigned short Ah[2][128][40], Al[2][128][40];
  __shared__ __align__(16) unsigned short Bh[2][64][40],  Bl[2][64][40];
  const int arow = tid >> 2;            // 0..63 (+64 for second A chunk)
  const int apart = (tid & 3) * 8;      // 8-elem (16 B) piece of a 32-elem row

  float4 a00, a01, a10, a11;            // A rows arow, arow+64 (8 f32 each)
  u16x8 pb, plb;                        // B hi/lo
#define LOADTILE(KT) do {                                                   \
    const size_t ko = (size_t)(KT) * 32 + apart;                            \
    const float* pa_ = A + (size_t)(m0 + arow) * 512 + ko;                  \
    a00 = *(const float4*)pa_;       a01 = *(const float4*)(pa_ + 4);       \
    a10 = *(const float4*)(pa_ + 64 * 512);                                 \
    a11 = *(const float4*)(pa_ + 64 * 512 + 4);                             \
    pb  = *(const u16x8*)(BH + (size_t)(n0 + arow) * 512 + ko);             \
    plb = *(const u16x8*)(BL + (size_t)(n0 + arow) * 512 + ko);             \
  } while (0)
#define STORETILE(BUF) do {                                                 \
    u16x8 h0_, l0_, h1_, l1_;                                               \
    split8(a00, a01, h0_, l0_);                                             \
    split8(a10, a11, h1_, l1_);                                             \
    *(u16x8*)&Ah[BUF][arow][apart] = h0_;                                   \
    *(u16x8*)&Ah[BUF][arow + 64][apart] = h1_;                              \
    *(u16x8*)&Al[BUF][arow][apart] = l0_;                                   \
    *(u16x8*)&Al[BUF][arow + 64][apart] = l1_;                              \
    *(u16x8*)&Bh[BUF][arow][apart] = pb;                                    \
    *(u16x8*)&Bl[BUF][arow][apart] = plb;                                   \
  } while (0)

  f32x4 accm[4][2], acce[4][2];
  #pragma unroll
  for (int mt = 0; mt < 4; ++mt)
    #pragma unroll
    for (int nt = 0; nt < 2; ++nt) {
      accm[mt][nt] = (f32x4){0.f, 0.f, 0.f, 0.f};
      acce[mt][nt] = (f32x4){0.f, 0.f, 0.f, 0.f};
    }

  // prologue: stage tile 0 into buf 0
  LOADTILE(0);
  STORETILE(0);
  __syncthreads();

  for (int kt = 0; kt < 16; ++kt) {
    const int cur = kt & 1;
    if (kt + 1 < 16) LOADTILE(kt + 1);  // issue early; hides under compute
    bf16x8 ah[4], al[4], bh[2], bl[2];
    #pragma unroll
    for (int mt = 0; mt < 4; ++mt) {
      ah[mt] = *(const bf16x8*)&Ah[cur][wm * 64 + mt * 16 + r16][g * 8];
      al[mt] = *(const bf16x8*)&Al[cur][wm * 64 + mt * 16 + r16][g * 8];
    }
    #pragma unroll
    for (int nt = 0; nt < 2; ++nt) {
      bh[nt] = *(const bf16x8*)&Bh[cur][wn * 32 + nt * 16 + r16][g * 8];
      bl[nt] = *(const bf16x8*)&Bl[cur][wn * 32 + nt * 16 + r16][g * 8];
    }
    #pragma unroll
    for (int mt = 0; mt < 4; ++mt)
      #pragma unroll
      for (int nt = 0; nt < 2; ++nt) {
        accm[mt][nt] = __builtin_amdgcn_mfma_f32_16x16x32_bf16(ah[mt], bh[nt], accm[mt][nt], 0, 0, 0);
        acce[mt][nt] = __builtin_amdgcn_mfma_f32_16x16x32_bf16(al[mt], bh[nt], acce[mt][nt], 0, 0, 0);
        acce[mt][nt] = __builtin_amdgcn_mfma_f32_16x16x32_bf16(ah[mt], bl[nt], acce[mt][nt], 0, 0, 0);
      }
    if (kt + 1 < 16) STORETILE(cur ^ 1);  // other buffer: no read/write hazard
    __syncthreads();                       // single barrier per k-tile
  }
#undef LOADTILE
#undef STORETILE

  #pragma unroll
  for (int mt = 0; mt < 4; ++mt)
    #pragma unroll
    for (int nt = 0; nt < 2; ++nt)
      #pragma unroll
      for (int j = 0; j < 4; ++j) {
        float vsum = accm[mt][nt][j] + acce[mt][nt][j];
        int row = m0 + wm * 64 + mt * 16 + g * 4 + j;
        int col = n0 + wn * 32 + nt * 16 + r16;
        C[(size_t)row * 512 + col] = __builtin_amdgcn_exp2f(vsum * K2SCALE);
      }
}

// ---------------- fused scores + softmax + context (unchanged) -----------------
__global__ __launch_bounds__(512) void attn(
    const float* __restrict__ ws, const float* __restrict__ uh,
    const float* __restrict__ enc, const float* __restrict__ va,
    float* __restrict__ out_c, float* __restrict__ out_e)
{
  const int tid  = threadIdx.x;
  const int wave = tid >> 6;
  const int lane = tid & 63;
  const int b  = blockIdx.x >> 6;          // TD/QT = 64 tiles per batch
  const int q0 = (blockIdx.x & 63) * QT;
  __shared__ float s_sc[QT][TE];           // 4 KB
  __shared__ float red[3][QT][DE];         // 24 KB, context partials
  const int fbase = lane * 8;              // lane owns 8 contiguous f

  float4 v0 = *(const float4*)(va + fbase);
  float4 v1 = *(const float4*)(va + fbase + 4);
  float v[8] = {v0.x, v0.y, v0.z, v0.w, v1.x, v1.y, v1.z, v1.w};

  float eu[QT][8];
  #pragma unroll
  for (int q = 0; q < QT; ++q) {
    const float* up = uh + (size_t)(b * TD + q0 + q) * DE + fbase;
    float4 u0 = *(const float4*)(up);
    float4 u1 = *(const float4*)(up + 4);
    eu[q][0] = u0.x; eu[q][1] = u0.y; eu[q][2] = u0.z; eu[q][3] = u0.w;
    eu[q][4] = u1.x; eu[q][5] = u1.y; eu[q][6] = u1.z; eu[q][7] = u1.w;
  }

  const int t0 = wave * 32;
  const float* wp = ws + (size_t)(b * TE + t0) * DE + fbase;
  float4 w0 = *(const float4*)(wp);
  float4 w1 = *(const float4*)(wp + 4);
  for (int t = t0; t < t0 + 32; ++t) {
    float cw[8] = {w0.x, w0.y, w0.z, w0.w, w1.x, w1.y, w1.z, w1.w};
    wp += DE;
    w0 = *(const float4*)(wp);
    w1 = *(const float4*)(wp + 4);
    float a[QT];
    #pragma unroll
    for (int q = 0; q < QT; ++q) {
      float A0 = fmaf(cw[0], eu[q][0], 1.f);
      float A1 = fmaf(cw[1], eu[q][1], 1.f);
      float A2 = fmaf(cw[2], eu[q][2], 1.f);
      float A3 = fmaf(cw[3], eu[q][3], 1.f);
      float B0 = fmaf(cw[4], eu[q][4], 1.f);
      float B1 = fmaf(cw[5], eu[q][5], 1.f);
      float B2 = fmaf(cw[6], eu[q][6], 1.f);
      float B3 = fmaf(cw[7], eu[q][7], 1.f);
      float n1 = fmaf(v[1], A0, v[0] * A1);
      float d1 = A0 * A1;
      float n2 = fmaf(v[3], A2, v[2] * A3);
      float d2 = A2 * A3;
      float N1 = fmaf(n2, d1, n1 * d2);
      float D1 = d1 * d2;
      float n3 = fmaf(v[5], B0, v[4] * B1);
      float d3 = B0 * B1;
      float n4 = fmaf(v[7], B2, v[6] * B3);
      float d4 = B2 * B3;
      float N2 = fmaf(n4, d3, n3 * d4);
      float D2 = d3 * d4;
      float s = N1 * __builtin_amdgcn_rcpf(D1);
      a[q] = fmaf(N2, __builtin_amdgcn_rcpf(D2), s);
    }
    {
      const bool h1 = lane & 1;
      float m0 = h1 ? a[1] : a[0], o0 = h1 ? a[0] : a[1];
      float m1 = h1 ? a[3] : a[2], o1 = h1 ? a[2] : a[3];
      float r0 = m0 + __shfl_xor(o0, 1, 64);
      float r1 = m1 + __shfl_xor(o1, 1, 64);
      const bool h2 = lane & 2;
      float mm = h2 ? r1 : r0, oo = h2 ? r0 : r1;
      float r = mm + __shfl_xor(oo, 2, 64);
      r += __shfl_xor(r, 4, 64);
      r += __shfl_xor(r, 8, 64);
      r += __shfl_xor(r, 16, 64);
      r += __shfl_xor(r, 32, 64);
      if (lane < QT) s_sc[lane][t] = -2.f * r;
    }
  }
  __syncthreads();

  if (wave < QT) {
    const int r = wave;
    float x[4];
    #pragma unroll
    for (int i = 0; i < 4; ++i) x[i] = s_sc[r][lane + 64 * i];
    float m = fmaxf(fmaxf(x[0], x[1]), fmaxf(x[2], x[3]));
    #pragma unroll
    for (int off = 32; off >= 1; off >>= 1) m = fmaxf(m, __shfl_xor(m, off, 64));
    const float L2E = 1.4426950408889634f;
    float ssum = 0.f;
    #pragma unroll
    for (int i = 0; i < 4; ++i) { x[i] = __builtin_amdgcn_exp2f((x[i] - m) * L2E); ssum += x[i]; }
    #pragma unroll
    for (int off = 32; off >= 1; off >>= 1) ssum += __shfl_xor(ssum, off, 64);
    float inv = 1.f / ssum;
    float* oe = out_e + (size_t)(b * TD + q0 + r) * TE;
    #pragma unroll
    for (int i = 0; i < 4; ++i) {
      float e = x[i] * inv;
      s_sc[r][lane + 64 * i] = e;
      oe[lane + 64 * i] = e;
    }
  }
  __syncthreads();

  {
    const int fgrp = tid >> 7;           // 0..3
    const int f4   = (tid & 127) * 4;
    float4 c[QT];
    #pragma unroll
    for (int q = 0; q < QT; ++q) c[q] = make_float4(0.f, 0.f, 0.f, 0.f);
    const float* eb = enc + (size_t)b * TE * DE + f4;
    const int tb = fgrp * 64;
    #pragma unroll 4
    for (int t = tb; t < tb + 64; ++t) {
      float4 ee = *(const float4*)(eb + (size_t)t * DE);
      #pragma unroll
      for (int q = 0; q < QT; ++q) {
        float w = s_sc[q][t];
        c[q].x = fmaf(w, ee.x, c[q].x);
        c[q].y = fmaf(w, ee.y, c[q].y);
        c[q].z = fmaf(w, ee.z, c[q].z);
        c[q].w = fmaf(w, ee.w, c[q].w);
      }
    }
    if (fgrp > 0) {
      #pragma unroll
      for (int q = 0; q < QT; ++q) *(float4*)&red[fgrp - 1][q][f4] = c[q];
    }
    __syncthreads();
    if (fgrp == 0) {
      #pragma unroll
      for (int q = 0; q < QT; ++q) {
        float4 r1 = *(const float4*)&red[0][q][f4];
        float4 r2 = *(const float4*)&red[1][q][f4];
        float4 r3 = *(const float4*)&red[2][q][f4];
        c[q].x += (r1.x + r2.x) + r3.x;
        c[q].y += (r1.y + r2.y) + r3.y;
        c[q].z += (r1.z + r2.z) + r3.z;
        c[q].w += (r1.w + r2.w) + r3.w;
        *(float4*)(out_c + (size_t)(b * TD + q0 + q) * DE + f4) = c[q];
      }
    }
  }
}

extern "C" void kernel_launch(void* const* d_in, const int* in_sizes, int n_in,
                              void* d_out, int out_size, void* d_ws, size_t ws_size,
                              hipStream_t stream) {
  const float* enc = (const float*)d_in[0];
  const float* dec = (const float*)d_in[1];
  const float* Wa  = (const float*)d_in[2];
  const float* Ua  = (const float*)d_in[3];
  const float* Va  = (const float*)d_in[4];
  float* out_c = (float*)d_out;
  float* out_e = out_c + (size_t)NB * TD * DE;          // c first, then e

  // workspace layout (10 MB):
  float* ws = (float*)d_ws;                             // ew = e^{2Ws}: 4 MB
  float* uh = ws + 1048576;                             // eu = e^{2Uh}: 4 MB
  unsigned short* BHw = (unsigned short*)(uh + 1048576);// 0.5 MB each
  unsigned short* BLw = BHw + 262144;
  unsigned short* BHu = BLw + 262144;
  unsigned short* BLu = BHu + 262144;

  convB<<<dim3(16, 16, 2), dim3(256), 0, stream>>>(Wa, BHw, BLw, Ua, BHu, BLu);
  gemm_mfma<<<dim3(8, 16, 2), dim3(256), 0, stream>>>(
      enc, BHw, BLw, ws, dec, BHu, BLu, uh);
  attn<<<dim3(NB * (TD / QT)), dim3(512), 0, stream>>>(
      ws, uh, enc, Va, out_c, out_e);
}

// Round 6
// 69.010 us; speedup vs baseline: 1.8660x; 1.0446x over previous
//
#include <hip/hip_runtime.h>

#define NB 8
#define TE 256
#define TD 256
#define DE 512
#define QT 4

// K2 = 2*log2(e): exp2(K2*x) = e^{2x}; tanh(x) = 1 - 2/(e^{2x}+1).
#define K2SCALE 2.8853900817779268f

typedef short bf16x8 __attribute__((ext_vector_type(8)));           // 8 bf16 (4 VGPR)
typedef float f32x4 __attribute__((ext_vector_type(4)));            // MFMA acc
typedef unsigned short u16x8 __attribute__((ext_vector_type(8)));   // 16 B staging

// round-to-nearest-even f32 -> bf16
static __device__ __forceinline__ unsigned short f2bf(float x) {
  unsigned int u = __float_as_uint(x);
  u += 0x7fffu + ((u >> 16) & 1u);
  return (unsigned short)(u >> 16);
}

// split f32 -> hi (ROUNDED bf16) + lo (rounded residual).
// |x-(hi+lo)| <= 2^-17|x|; dropped AL*BL term <= 2^-18|A||B| (rounded hi keeps
// |lo| <= 2^-9|x|, vs 2^-8 for truncated hi -> one extra bit of accuracy).
static __device__ __forceinline__ void split8(
    const float4& x0, const float4& x1, u16x8& h, u16x8& l) {
  float xs[8] = {x0.x, x0.y, x0.z, x0.w, x1.x, x1.y, x1.z, x1.w};
  #pragma unroll
  for (int j = 0; j < 8; ++j) {
    unsigned short hh = f2bf(xs[j]);
    float hf = __uint_as_float((unsigned int)hh << 16);
    h[j] = hh;
    l[j] = f2bf(xs[j] - hf);
  }
}

// ---- convB: W [512x512] f32 -> TRANSPOSED hi/lo bf16 BT[n][k] (32x32 tiles) ----
// grid (16, 16, 2), 256 thr.
__global__ __launch_bounds__(256) void convB(
    const float* __restrict__ w0, unsigned short* __restrict__ h0, unsigned short* __restrict__ l0,
    const float* __restrict__ w1, unsigned short* __restrict__ h1, unsigned short* __restrict__ l1)
{
  const float* W = blockIdx.z ? w1 : w0;
  unsigned short* H = blockIdx.z ? h1 : h0;
  unsigned short* L = blockIdx.z ? l1 : l0;
  __shared__ unsigned short sh[32][33], sl[32][33];
  const int t = threadIdx.x;
  const int k0 = blockIdx.y * 32, n0 = blockIdx.x * 32;
  const int r = t >> 3, c = (t & 7) * 4;
  float4 x = *(const float4*)(W + (size_t)(k0 + r) * DE + n0 + c);
  float xs[4] = {x.x, x.y, x.z, x.w};
  #pragma unroll
  for (int j = 0; j < 4; ++j) {
    unsigned short hh = f2bf(xs[j]);
    float hf = __uint_as_float((unsigned int)hh << 16);
    sh[r][c + j] = hh;
    sl[r][c + j] = f2bf(xs[j] - hf);
  }
  __syncthreads();
  ushort4 oh, ol;
  oh.x = sh[c + 0][r]; oh.y = sh[c + 1][r]; oh.z = sh[c + 2][r]; oh.w = sh[c + 3][r];
  ol.x = sl[c + 0][r]; ol.y = sl[c + 1][r]; ol.z = sl[c + 2][r]; ol.w = sl[c + 3][r];
  *(ushort4*)(H + (size_t)(n0 + r) * DE + k0 + c) = oh;
  *(ushort4*)(L + (size_t)(n0 + r) * DE + k0 + c) = ol;
}

// ---- gemm_mfma: C = exp2(K2 * A@B), A f32 split in-register, dbuf LDS ---------
// A: f32 [2048x512]; B: transposed BH/BL bf16 [n][k]. acc = AH*BH + AL*BH + AH*BL.
// BM=64 BN=64 KT=32, 256 thr (4 waves 2x2), wave-tile 32x32 = 2x2 16x16 frags.
// grid (8, 32, 2) = 512 blocks -> 2 blocks/CU, 2 waves/SIMD (occupancy fix vs
// R5's 1 wave/SIMD). ONE barrier per k-tile. C/D: col=lane&15, row=(lane>>4)*4+j.
__global__ __launch_bounds__(256) void gemm_mfma(
    const float* __restrict__ A0,
    const unsigned short* __restrict__ BH0, const unsigned short* __restrict__ BL0,
    float* __restrict__ C0,
    const float* __restrict__ A1,
    const unsigned short* __restrict__ BH1, const unsigned short* __restrict__ BL1,
    float* __restrict__ C1)
{
  const float*          A  = blockIdx.z ? A1  : A0;
  const unsigned short* BH = blockIdx.z ? BH1 : BH0;
  const unsigned short* BL = blockIdx.z ? BL1 : BL0;
  float*                C  = blockIdx.z ? C1  : C0;
  const int tid  = threadIdx.x;
  const int lane = tid & 63;
  const int wave = tid >> 6;
  const int wm = wave >> 1, wn = wave & 1;
  const int g = lane >> 4, r16 = lane & 15;
  const int m0 = blockIdx.y * 64, n0 = blockIdx.x * 64;
  // double-buffered LDS, rows padded to 40 ushorts (80 B): 40 KB total
  __shared__ __align__(16) unsigned short Ah[2][64][40], Al[2][64][40];
  __shared__ __align__(16) unsigned short Bh[2][64][40], Bl[2][64][40];
  const int arow = tid >> 2;            // 0..63
  const int apart = (tid & 3) * 8;      // 8-elem (16 B) piece of a 32-elem row

  float4 a00, a01;                      // A row arow (8 f32)
  u16x8 pb, plb;                        // B hi/lo
#define LOADTILE(KT) do {                                                   \
    const size_t ko = (size_t)(KT) * 32 + apart;                            \
    const float* pa_ = A + (size_t)(m0 + arow) * 512 + ko;                  \
    a00 = *(const float4*)pa_;  a01 = *(const float4*)(pa_ + 4);            \
    pb  = *(const u16x8*)(BH + (size_t)(n0 + arow) * 512 + ko);             \
    plb = *(const u16x8*)(BL + (size_t)(n0 + arow) * 512 + ko);             \
  } while (0)
#define STORETILE(BUF) do {                                                 \
    u16x8 h0_, l0_;                                                         \
    split8(a00, a01, h0_, l0_);                                             \
    *(u16x8*)&Ah[BUF][arow][apart] = h0_;                                   \
    *(u16x8*)&Al[BUF][arow][apart] = l0_;                                   \
    *(u16x8*)&Bh[BUF][arow][apart] = pb;                                    \
    *(u16x8*)&Bl[BUF][arow][apart] = plb;                                   \
  } while (0)

  f32x4 accm[2][2], acce[2][2];
  #pragma unroll
  for (int mt = 0; mt < 2; ++mt)
    #pragma unroll
    for (int nt = 0; nt < 2; ++nt) {
      accm[mt][nt] = (f32x4){0.f, 0.f, 0.f, 0.f};
      acce[mt][nt] = (f32x4){0.f, 0.f, 0.f, 0.f};
    }

  LOADTILE(0);
  STORETILE(0);
  __syncthreads();

  for (int kt = 0; kt < 16; ++kt) {
    const int cur = kt & 1;
    if (kt + 1 < 16) LOADTILE(kt + 1);  // issue early; hides under compute
    bf16x8 ah[2], al[2], bh[2], bl[2];
    #pragma unroll
    for (int mt = 0; mt < 2; ++mt) {
      ah[mt] = *(const bf16x8*)&Ah[cur][wm * 32 + mt * 16 + r16][g * 8];
      al[mt] = *(const bf16x8*)&Al[cur][wm * 32 + mt * 16 + r16][g * 8];
    }
    #pragma unroll
    for (int nt = 0; nt < 2; ++nt) {
      bh[nt] = *(const bf16x8*)&Bh[cur][wn * 32 + nt * 16 + r16][g * 8];
      bl[nt] = *(const bf16x8*)&Bl[cur][wn * 32 + nt * 16 + r16][g * 8];
    }
    #pragma unroll
    for (int mt = 0; mt < 2; ++mt)
      #pragma unroll
      for (int nt = 0; nt < 2; ++nt) {
        accm[mt][nt] = __builtin_amdgcn_mfma_f32_16x16x32_bf16(ah[mt], bh[nt], accm[mt][nt], 0, 0, 0);
        acce[mt][nt] = __builtin_amdgcn_mfma_f32_16x16x32_bf16(al[mt], bh[nt], acce[mt][nt], 0, 0, 0);
        acce[mt][nt] = __builtin_amdgcn_mfma_f32_16x16x32_bf16(ah[mt], bl[nt], acce[mt][nt], 0, 0, 0);
      }
    if (kt + 1 < 16) STORETILE(cur ^ 1);  // other buffer: no hazard
    __syncthreads();                       // single barrier per k-tile
  }
#undef LOADTILE
#undef STORETILE

  #pragma unroll
  for (int mt = 0; mt < 2; ++mt)
    #pragma unroll
    for (int nt = 0; nt < 2; ++nt)
      #pragma unroll
      for (int j = 0; j < 4; ++j) {
        float vsum = accm[mt][nt][j] + acce[mt][nt][j];
        int row = m0 + wm * 32 + mt * 16 + g * 4 + j;
        int col = n0 + wn * 32 + nt * 16 + r16;
        C[(size_t)row * 512 + col] = __builtin_amdgcn_exp2f(vsum * K2SCALE);
      }
}

// ---------------- fused scores + softmax + context -----------------------------
// block = 512 thr (8 waves), handles (b, q-tile of QT=4). grid = 8*64 = 512.
// ws/uh hold ew = e^{2Ws}, eu = e^{2Uh}. Score (up to softmax-invariant const):
//   s[q,t] = -2 * sum_f v[f] / (ew[t,f]*eu[q,f] + 1)
// 4-way rcp combining. Score loop batches 4 t-rows per butterfly: value-halving
// over 16 values = 6 dependent shfl levels per 4 t (vs 28 for 4 separate
// butterflies) -- the shfl chain was the score phase's hidden serial cost.
__global__ __launch_bounds__(512, 4) void attn(
    const float* __restrict__ ws, const float* __restrict__ uh,
    const float* __restrict__ enc, const float* __restrict__ va,
    float* __restrict__ out_c, float* __restrict__ out_e)
{
  const int tid  = threadIdx.x;
  const int wave = tid >> 6;
  const int lane = tid & 63;
  const int b  = blockIdx.x >> 6;          // TD/QT = 64 tiles per batch
  const int q0 = (blockIdx.x & 63) * QT;
  __shared__ float s_sc[QT][TE];           // 4 KB
  __shared__ float red[3][QT][DE];         // 24 KB, context partials
  const int fbase = lane * 8;              // lane owns 8 contiguous f

  float4 v0 = *(const float4*)(va + fbase);
  float4 v1 = *(const float4*)(va + fbase + 4);
  float v[8] = {v0.x, v0.y, v0.z, v0.w, v1.x, v1.y, v1.z, v1.w};

  float eu[QT][8];
  #pragma unroll
  for (int q = 0; q < QT; ++q) {
    const float* up = uh + (size_t)(b * TD + q0 + q) * DE + fbase;
    float4 u0 = *(const float4*)(up);
    float4 u1 = *(const float4*)(up + 4);
    eu[q][0] = u0.x; eu[q][1] = u0.y; eu[q][2] = u0.z; eu[q][3] = u0.w;
    eu[q][4] = u1.x; eu[q][5] = u1.y; eu[q][6] = u1.z; eu[q][7] = u1.w;
  }

  // ---- scores: wave owns t in [wave*32, wave*32+32), 4 t per iteration ----
  const int t0 = wave * 32;
  const float* wsb = ws + (size_t)b * TE * DE + fbase;
  for (int tt = t0; tt < t0 + 32; tt += 4) {
    float wr[4][8];
    #pragma unroll
    for (int dt = 0; dt < 4; ++dt) {       // 4 rows' loads issue back-to-back
      const float* wp = wsb + (size_t)(tt + dt) * DE;
      float4 w0 = *(const float4*)(wp);
      float4 w1 = *(const float4*)(wp + 4);
      wr[dt][0] = w0.x; wr[dt][1] = w0.y; wr[dt][2] = w0.z; wr[dt][3] = w0.w;
      wr[dt][4] = w1.x; wr[dt][5] = w1.y; wr[dt][6] = w1.z; wr[dt][7] = w1.w;
    }
    float a[16];                            // a[q + 4*dt]
    #pragma unroll
    for (int dt = 0; dt < 4; ++dt)
      #pragma unroll
      for (int q = 0; q < QT; ++q) {
        float A0 = fmaf(wr[dt][0], eu[q][0], 1.f);
        float A1 = fmaf(wr[dt][1], eu[q][1], 1.f);
        float A2 = fmaf(wr[dt][2], eu[q][2], 1.f);
        float A3 = fmaf(wr[dt][3], eu[q][3], 1.f);
        float B0 = fmaf(wr[dt][4], eu[q][4], 1.f);
        float B1 = fmaf(wr[dt][5], eu[q][5], 1.f);
        float B2 = fmaf(wr[dt][6], eu[q][6], 1.f);
        float B3 = fmaf(wr[dt][7], eu[q][7], 1.f);
        float n1 = fmaf(v[1], A0, v[0] * A1);
        float d1 = A0 * A1;
        float n2 = fmaf(v[3], A2, v[2] * A3);
        float d2 = A2 * A3;
        float N1 = fmaf(n2, d1, n1 * d2);
        float D1 = d1 * d2;
        float n3 = fmaf(v[5], B0, v[4] * B1);
        float d3 = B0 * B1;
        float n4 = fmaf(v[7], B2, v[6] * B3);
        float d4 = B2 * B3;
        float N2 = fmaf(n4, d3, n3 * d4);
        float D2 = d3 * d4;
        float s = N1 * __builtin_amdgcn_rcpf(D1);
        a[q + 4 * dt] = fmaf(N2, __builtin_amdgcn_rcpf(D2), s);
      }
    // value-halving butterfly over 16 values: lane l<16 ends with idx = l
    // (bit k of final idx selected by lane bit k at step 2^k).
    float b8[8];
    #pragma unroll
    for (int k = 0; k < 8; ++k) {
      float mine = (lane & 1) ? a[2 * k + 1] : a[2 * k];
      float oth  = (lane & 1) ? a[2 * k]     : a[2 * k + 1];
      b8[k] = mine + __shfl_xor(oth, 1, 64);
    }
    float c4[4];
    #pragma unroll
    for (int k = 0; k < 4; ++k) {
      float mine = (lane & 2) ? b8[2 * k + 1] : b8[2 * k];
      float oth  = (lane & 2) ? b8[2 * k]     : b8[2 * k + 1];
      c4[k] = mine + __shfl_xor(oth, 2, 64);
    }
    float d2v[2];
    #pragma unroll
    for (int k = 0; k < 2; ++k) {
      float mine = (lane & 4) ? c4[2 * k + 1] : c4[2 * k];
      float oth  = (lane & 4) ? c4[2 * k]     : c4[2 * k + 1];
      d2v[k] = mine + __shfl_xor(oth, 4, 64);
    }
    float mine = (lane & 8) ? d2v[1] : d2v[0];
    float oth  = (lane & 8) ? d2v[0] : d2v[1];
    float e = mine + __shfl_xor(oth, 8, 64);
    e += __shfl_xor(e, 16, 64);
    e += __shfl_xor(e, 32, 64);
    if (lane < 16) s_sc[lane & 3][tt + (lane >> 2)] = -2.f * e;
  }
  __syncthreads();

  // ---- softmax: waves 0..3 handle row = wave; waves 4..7 wait ----
  if (wave < QT) {
    const int r = wave;
    float x[4];
    #pragma unroll
    for (int i = 0; i < 4; ++i) x[i] = s_sc[r][lane + 64 * i];
    float m = fmaxf(fmaxf(x[0], x[1]), fmaxf(x[2], x[3]));
    #pragma unroll
    for (int off = 32; off >= 1; off >>= 1) m = fmaxf(m, __shfl_xor(m, off, 64));
    const float L2E = 1.4426950408889634f;
    float ssum = 0.f;
    #pragma unroll
    for (int i = 0; i < 4; ++i) { x[i] = __builtin_amdgcn_exp2f((x[i] - m) * L2E); ssum += x[i]; }
    #pragma unroll
    for (int off = 32; off >= 1; off >>= 1) ssum += __shfl_xor(ssum, off, 64);
    float inv = 1.f / ssum;
    float* oe = out_e + (size_t)(b * TD + q0 + r) * TE;
    #pragma unroll
    for (int i = 0; i < 4; ++i) {
      float e = x[i] * inv;
      s_sc[r][lane + 64 * i] = e;
      oe[lane + 64 * i] = e;
    }
  }
  __syncthreads();

  // ---- context: c[q][f4..f4+3] = sum_t e[q][t]*enc[b][t][f4..f4+3] ----
  {
    const int fgrp = tid >> 7;           // 0..3
    const int f4   = (tid & 127) * 4;
    float4 c[QT];
    #pragma unroll
    for (int q = 0; q < QT; ++q) c[q] = make_float4(0.f, 0.f, 0.f, 0.f);
    const float* eb = enc + (size_t)b * TE * DE + f4;
    const int tb = fgrp * 64;
    #pragma unroll 4
    for (int t = tb; t < tb + 64; ++t) {
      float4 ee = *(const float4*)(eb + (size_t)t * DE);
      #pragma unroll
      for (int q = 0; q < QT; ++q) {
        float w = s_sc[q][t];
        c[q].x = fmaf(w, ee.x, c[q].x);
        c[q].y = fmaf(w, ee.y, c[q].y);
        c[q].z = fmaf(w, ee.z, c[q].z);
        c[q].w = fmaf(w, ee.w, c[q].w);
      }
    }
    if (fgrp > 0) {
      #pragma unroll
      for (int q = 0; q < QT; ++q) *(float4*)&red[fgrp - 1][q][f4] = c[q];
    }
    __syncthreads();
    if (fgrp == 0) {
      #pragma unroll
      for (int q = 0; q < QT; ++q) {
        float4 r1 = *(const float4*)&red[0][q][f4];
        float4 r2 = *(const float4*)&red[1][q][f4];
        float4 r3 = *(const float4*)&red[2][q][f4];
        c[q].x += (r1.x + r2.x) + r3.x;
        c[q].y += (r1.y + r2.y) + r3.y;
        c[q].z += (r1.z + r2.z) + r3.z;
        c[q].w += (r1.w + r2.w) + r3.w;
        *(float4*)(out_c + (size_t)(b * TD + q0 + q) * DE + f4) = c[q];
      }
    }
  }
}

extern "C" void kernel_launch(void* const* d_in, const int* in_sizes, int n_in,
                              void* d_out, int out_size, void* d_ws, size_t ws_size,
                              hipStream_t stream) {
  const float* enc = (const float*)d_in[0];
  const float* dec = (const float*)d_in[1];
  const float* Wa  = (const float*)d_in[2];
  const float* Ua  = (const float*)d_in[3];
  const float* Va  = (const float*)d_in[4];
  float* out_c = (float*)d_out;
  float* out_e = out_c + (size_t)NB * TD * DE;          // c first, then e

  // workspace layout (10 MB):
  float* ws = (float*)d_ws;                             // ew = e^{2Ws}: 4 MB
  float* uh = ws + 1048576;                             // eu = e^{2Uh}: 4 MB
  unsigned short* BHw = (unsigned short*)(uh + 1048576);// 0.5 MB each
  unsigned short* BLw = BHw + 262144;
  unsigned short* BHu = BLw + 262144;
  unsigned short* BLu = BHu + 262144;

  convB<<<dim3(16, 16, 2), dim3(256), 0, stream>>>(Wa, BHw, BLw, Ua, BHu, BLu);
  gemm_mfma<<<dim3(8, 32, 2), dim3(256), 0, stream>>>(
      enc, BHw, BLw, ws, dec, BHu, BLu, uh);
  attn<<<dim3(NB * (TD / QT)), dim3(512), 0, stream>>>(
      ws, uh, enc, Va, out_c, out_e);
}

// Round 7
// 68.717 us; speedup vs baseline: 1.8740x; 1.0043x over previous
//
#include <hip/hip_runtime.h>

#define NB 8
#define TE 256
#define TD 256
#define DE 512
#define QT 4

// K2 = 2*log2(e): exp2(K2*x) = e^{2x}; tanh(x) = 1 - 2/(e^{2x}+1).
#define K2SCALE 2.8853900817779268f

typedef short bf16x8 __attribute__((ext_vector_type(8)));           // 8 bf16 (4 VGPR)
typedef float f32x4 __attribute__((ext_vector_type(4)));            // MFMA acc
typedef unsigned short u16x8 __attribute__((ext_vector_type(8)));   // 16 B staging

// round-to-nearest-even f32 -> bf16
static __device__ __forceinline__ unsigned short f2bf(float x) {
  unsigned int u = __float_as_uint(x);
  u += 0x7fffu + ((u >> 16) & 1u);
  return (unsigned short)(u >> 16);
}

// split f32 -> hi (ROUNDED bf16) + lo (rounded residual).
static __device__ __forceinline__ void split8(
    const float4& x0, const float4& x1, u16x8& h, u16x8& l) {
  float xs[8] = {x0.x, x0.y, x0.z, x0.w, x1.x, x1.y, x1.z, x1.w};
  #pragma unroll
  for (int j = 0; j < 8; ++j) {
    unsigned short hh = f2bf(xs[j]);
    float hf = __uint_as_float((unsigned int)hh << 16);
    h[j] = hh;
    l[j] = f2bf(xs[j] - hf);
  }
}

// ---- convB: W [512x512] f32 -> TRANSPOSED hi/lo bf16 BT[n][k] (32x32 tiles) ----
// grid (16, 16, 2), 256 thr.
__global__ __launch_bounds__(256) void convB(
    const float* __restrict__ w0, unsigned short* __restrict__ h0, unsigned short* __restrict__ l0,
    const float* __restrict__ w1, unsigned short* __restrict__ h1, unsigned short* __restrict__ l1)
{
  const float* W = blockIdx.z ? w1 : w0;
  unsigned short* H = blockIdx.z ? h1 : h0;
  unsigned short* L = blockIdx.z ? l1 : l0;
  __shared__ unsigned short sh[32][33], sl[32][33];
  const int t = threadIdx.x;
  const int k0 = blockIdx.y * 32, n0 = blockIdx.x * 32;
  const int r = t >> 3, c = (t & 7) * 4;
  float4 x = *(const float4*)(W + (size_t)(k0 + r) * DE + n0 + c);
  float xs[4] = {x.x, x.y, x.z, x.w};
  #pragma unroll
  for (int j = 0; j < 4; ++j) {
    unsigned short hh = f2bf(xs[j]);
    float hf = __uint_as_float((unsigned int)hh << 16);
    sh[r][c + j] = hh;
    sl[r][c + j] = f2bf(xs[j] - hf);
  }
  __syncthreads();
  ushort4 oh, ol;
  oh.x = sh[c + 0][r]; oh.y = sh[c + 1][r]; oh.z = sh[c + 2][r]; oh.w = sh[c + 3][r];
  ol.x = sl[c + 0][r]; ol.y = sl[c + 1][r]; ol.z = sl[c + 2][r]; ol.w = sl[c + 3][r];
  *(ushort4*)(H + (size_t)(n0 + r) * DE + k0 + c) = oh;
  *(ushort4*)(L + (size_t)(n0 + r) * DE + k0 + c) = ol;
}

// ---- gemm_mfma: C = exp2(K2 * A@B), A f32 split in-register, dbuf LDS ---------
// A: f32 [2048x512]; B: transposed BH/BL bf16 [n][k]. acc = AH*BH + AL*BH + AH*BL.
// BM=64 BN=64 KT=32, 256 thr (4 waves 2x2), wave-tile 32x32.
// 1D grid 512, XCD-clustered decode: the 8 n-blocks sharing one A-panel get
// block IDs congruent mod 8 -> same XCD under round-robin dispatch -> the
// A-panel re-reads (8x) hit that XCD's L2 instead of streaming from L3.
__global__ __launch_bounds__(256) void gemm_mfma(
    const float* __restrict__ A0,
    const unsigned short* __restrict__ BH0, const unsigned short* __restrict__ BL0,
    float* __restrict__ C0,
    const float* __restrict__ A1,
    const unsigned short* __restrict__ BH1, const unsigned short* __restrict__ BL1,
    float* __restrict__ C1)
{
  const int blk = blockIdx.x;
  const int xcd = blk & 7;
  const int j = blk >> 3;                   // 0..63
  const int panel = xcd * 8 + (j & 7);      // 0..63: (m-block, matrix) pair
  const int bx = j >> 3;                    // 0..7  n-block
  const int by = panel & 31;                // 0..31 m-block
  const int bz = panel >> 5;                // 0..1  matrix select
  const float*          A  = bz ? A1  : A0;
  const unsigned short* BH = bz ? BH1 : BH0;
  const unsigned short* BL = bz ? BL1 : BL0;
  float*                C  = bz ? C1  : C0;
  const int tid  = threadIdx.x;
  const int lane = tid & 63;
  const int wave = tid >> 6;
  const int wm = wave >> 1, wn = wave & 1;
  const int g = lane >> 4, r16 = lane & 15;
  const int m0 = by * 64, n0 = bx * 64;
  __shared__ __align__(16) unsigned short Ah[2][64][40], Al[2][64][40];
  __shared__ __align__(16) unsigned short Bh[2][64][40], Bl[2][64][40];
  const int arow = tid >> 2;            // 0..63
  const int apart = (tid & 3) * 8;      // 8-elem (16 B) piece of a 32-elem row

  float4 a00, a01;
  u16x8 pb, plb;
#define LOADTILE(KT) do {                                                   \
    const size_t ko = (size_t)(KT) * 32 + apart;                            \
    const float* pa_ = A + (size_t)(m0 + arow) * 512 + ko;                  \
    a00 = *(const float4*)pa_;  a01 = *(const float4*)(pa_ + 4);            \
    pb  = *(const u16x8*)(BH + (size_t)(n0 + arow) * 512 + ko);             \
    plb = *(const u16x8*)(BL + (size_t)(n0 + arow) * 512 + ko);             \
  } while (0)
#define STORETILE(BUF) do {                                                 \
    u16x8 h0_, l0_;                                                         \
    split8(a00, a01, h0_, l0_);                                             \
    *(u16x8*)&Ah[BUF][arow][apart] = h0_;                                   \
    *(u16x8*)&Al[BUF][arow][apart] = l0_;                                   \
    *(u16x8*)&Bh[BUF][arow][apart] = pb;                                    \
    *(u16x8*)&Bl[BUF][arow][apart] = plb;                                   \
  } while (0)

  f32x4 accm[2][2], acce[2][2];
  #pragma unroll
  for (int mt = 0; mt < 2; ++mt)
    #pragma unroll
    for (int nt = 0; nt < 2; ++nt) {
      accm[mt][nt] = (f32x4){0.f, 0.f, 0.f, 0.f};
      acce[mt][nt] = (f32x4){0.f, 0.f, 0.f, 0.f};
    }

  LOADTILE(0);
  STORETILE(0);
  __syncthreads();

  for (int kt = 0; kt < 16; ++kt) {
    const int cur = kt & 1;
    if (kt + 1 < 16) LOADTILE(kt + 1);  // issue early; hides under compute
    bf16x8 ah[2], al[2], bh[2], bl[2];
    #pragma unroll
    for (int mt = 0; mt < 2; ++mt) {
      ah[mt] = *(const bf16x8*)&Ah[cur][wm * 32 + mt * 16 + r16][g * 8];
      al[mt] = *(const bf16x8*)&Al[cur][wm * 32 + mt * 16 + r16][g * 8];
    }
    #pragma unroll
    for (int nt = 0; nt < 2; ++nt) {
      bh[nt] = *(const bf16x8*)&Bh[cur][wn * 32 + nt * 16 + r16][g * 8];
      bl[nt] = *(const bf16x8*)&Bl[cur][wn * 32 + nt * 16 + r16][g * 8];
    }
    #pragma unroll
    for (int mt = 0; mt < 2; ++mt)
      #pragma unroll
      for (int nt = 0; nt < 2; ++nt) {
        accm[mt][nt] = __builtin_amdgcn_mfma_f32_16x16x32_bf16(ah[mt], bh[nt], accm[mt][nt], 0, 0, 0);
        acce[mt][nt] = __builtin_amdgcn_mfma_f32_16x16x32_bf16(al[mt], bh[nt], acce[mt][nt], 0, 0, 0);
        acce[mt][nt] = __builtin_amdgcn_mfma_f32_16x16x32_bf16(ah[mt], bl[nt], acce[mt][nt], 0, 0, 0);
      }
    if (kt + 1 < 16) STORETILE(cur ^ 1);  // other buffer: no hazard
    __syncthreads();                       // single barrier per k-tile
  }
#undef LOADTILE
#undef STORETILE

  #pragma unroll
  for (int mt = 0; mt < 2; ++mt)
    #pragma unroll
    for (int nt = 0; nt < 2; ++nt)
      #pragma unroll
      for (int jj = 0; jj < 4; ++jj) {
        float vsum = accm[mt][nt][jj] + acce[mt][nt][jj];
        int row = m0 + wm * 32 + mt * 16 + g * 4 + jj;
        int col = n0 + wn * 32 + nt * 16 + r16;
        C[(size_t)row * 512 + col] = __builtin_amdgcn_exp2f(vsum * K2SCALE);
      }
}

// ---------------- fused scores + softmax + context -----------------------------
// block = 512 thr (8 waves), handles (b, q-tile of QT=4). grid = 8*64 = 512.
// XCD-locality swizzle: b = blockIdx.x & 7 -> under round-robin dispatch all 64
// blocks of batch b land on one XCD (exactly 2 blocks/CU on its 32 CUs), so
// ew[b] (512 KB) + enc[b] (512 KB) L2-reside there instead of 8 XCDs each
// re-pulling every batch's set from L3 (which made attn L3-BW-bound at ~48us).
// Score loop: R5's proven per-t form (1-deep prefetch + 7-shfl butterfly).
__global__ __launch_bounds__(512) void attn(
    const float* __restrict__ ws, const float* __restrict__ uh,
    const float* __restrict__ enc, const float* __restrict__ va,
    float* __restrict__ out_c, float* __restrict__ out_e)
{
  const int tid  = threadIdx.x;
  const int wave = tid >> 6;
  const int lane = tid & 63;
  const int b  = blockIdx.x & 7;           // XCD-locality: batch <-> XCD
  const int q0 = (blockIdx.x >> 3) * QT;
  __shared__ float s_sc[QT][TE];           // 4 KB
  __shared__ float red[3][QT][DE];         // 24 KB, context partials
  const int fbase = lane * 8;              // lane owns 8 contiguous f

  float4 v0 = *(const float4*)(va + fbase);
  float4 v1 = *(const float4*)(va + fbase + 4);
  float v[8] = {v0.x, v0.y, v0.z, v0.w, v1.x, v1.y, v1.z, v1.w};

  float eu[QT][8];
  #pragma unroll
  for (int q = 0; q < QT; ++q) {
    const float* up = uh + (size_t)(b * TD + q0 + q) * DE + fbase;
    float4 u0 = *(const float4*)(up);
    float4 u1 = *(const float4*)(up + 4);
    eu[q][0] = u0.x; eu[q][1] = u0.y; eu[q][2] = u0.z; eu[q][3] = u0.w;
    eu[q][4] = u1.x; eu[q][5] = u1.y; eu[q][6] = u1.z; eu[q][7] = u1.w;
  }

  // ---- scores: wave owns t in [wave*32, wave*32+32), 1-deep prefetch on ws ----
  const int t0 = wave * 32;
  const float* wp = ws + (size_t)(b * TE + t0) * DE + fbase;
  float4 w0 = *(const float4*)(wp);
  float4 w1 = *(const float4*)(wp + 4);
  for (int t = t0; t < t0 + 32; ++t) {
    float cw[8] = {w0.x, w0.y, w0.z, w0.w, w1.x, w1.y, w1.z, w1.w};
    // prefetch next row; last iteration reads one row past (lands in uh[0],
    // still inside the same workspace allocation) and is unused.
    wp += DE;
    w0 = *(const float4*)(wp);
    w1 = *(const float4*)(wp + 4);
    float a[QT];
    #pragma unroll
    for (int q = 0; q < QT; ++q) {
      float A0 = fmaf(cw[0], eu[q][0], 1.f);
      float A1 = fmaf(cw[1], eu[q][1], 1.f);
      float A2 = fmaf(cw[2], eu[q][2], 1.f);
      float A3 = fmaf(cw[3], eu[q][3], 1.f);
      float B0 = fmaf(cw[4], eu[q][4], 1.f);
      float B1 = fmaf(cw[5], eu[q][5], 1.f);
      float B2 = fmaf(cw[6], eu[q][6], 1.f);
      float B3 = fmaf(cw[7], eu[q][7], 1.f);
      float n1 = fmaf(v[1], A0, v[0] * A1);
      float d1 = A0 * A1;
      float n2 = fmaf(v[3], A2, v[2] * A3);
      float d2 = A2 * A3;
      float N1 = fmaf(n2, d1, n1 * d2);
      float D1 = d1 * d2;
      float n3 = fmaf(v[5], B0, v[4] * B1);
      float d3 = B0 * B1;
      float n4 = fmaf(v[7], B2, v[6] * B3);
      float d4 = B2 * B3;
      float N2 = fmaf(n4, d3, n3 * d4);
      float D2 = d3 * d4;
      float s = N1 * __builtin_amdgcn_rcpf(D1);
      a[q] = fmaf(N2, __builtin_amdgcn_rcpf(D2), s);
    }
    {
      const bool h1 = lane & 1;
      float m0 = h1 ? a[1] : a[0], o0 = h1 ? a[0] : a[1];
      float m1 = h1 ? a[3] : a[2], o1 = h1 ? a[2] : a[3];
      float r0 = m0 + __shfl_xor(o0, 1, 64);
      float r1 = m1 + __shfl_xor(o1, 1, 64);
      const bool h2 = lane & 2;
      float mm = h2 ? r1 : r0, oo = h2 ? r0 : r1;
      float r = mm + __shfl_xor(oo, 2, 64);
      r += __shfl_xor(r, 4, 64);
      r += __shfl_xor(r, 8, 64);
      r += __shfl_xor(r, 16, 64);
      r += __shfl_xor(r, 32, 64);
      if (lane < QT) s_sc[lane][t] = -2.f * r;
    }
  }
  __syncthreads();

  // ---- softmax: waves 0..3 handle row = wave; waves 4..7 wait ----
  if (wave < QT) {
    const int r = wave;
    float x[4];
    #pragma unroll
    for (int i = 0; i < 4; ++i) x[i] = s_sc[r][lane + 64 * i];
    float m = fmaxf(fmaxf(x[0], x[1]), fmaxf(x[2], x[3]));
    #pragma unroll
    for (int off = 32; off >= 1; off >>= 1) m = fmaxf(m, __shfl_xor(m, off, 64));
    const float L2E = 1.4426950408889634f;
    float ssum = 0.f;
    #pragma unroll
    for (int i = 0; i < 4; ++i) { x[i] = __builtin_amdgcn_exp2f((x[i] - m) * L2E); ssum += x[i]; }
    #pragma unroll
    for (int off = 32; off >= 1; off >>= 1) ssum += __shfl_xor(ssum, off, 64);
    float inv = 1.f / ssum;
    float* oe = out_e + (size_t)(b * TD + q0 + r) * TE;
    #pragma unroll
    for (int i = 0; i < 4; ++i) {
      float e = x[i] * inv;
      s_sc[r][lane + 64 * i] = e;
      oe[lane + 64 * i] = e;
    }
  }
  __syncthreads();

  // ---- context: c[q][f4..f4+3] = sum_t e[q][t]*enc[b][t][f4..f4+3] ----
  {
    const int fgrp = tid >> 7;           // 0..3
    const int f4   = (tid & 127) * 4;
    float4 c[QT];
    #pragma unroll
    for (int q = 0; q < QT; ++q) c[q] = make_float4(0.f, 0.f, 0.f, 0.f);
    const float* eb = enc + (size_t)b * TE * DE + f4;
    const int tb = fgrp * 64;
    #pragma unroll 4
    for (int t = tb; t < tb + 64; ++t) {
      float4 ee = *(const float4*)(eb + (size_t)t * DE);
      #pragma unroll
      for (int q = 0; q < QT; ++q) {
        float w = s_sc[q][t];
        c[q].x = fmaf(w, ee.x, c[q].x);
        c[q].y = fmaf(w, ee.y, c[q].y);
        c[q].z = fmaf(w, ee.z, c[q].z);
        c[q].w = fmaf(w, ee.w, c[q].w);
      }
    }
    if (fgrp > 0) {
      #pragma unroll
      for (int q = 0; q < QT; ++q) *(float4*)&red[fgrp - 1][q][f4] = c[q];
    }
    __syncthreads();
    if (fgrp == 0) {
      #pragma unroll
      for (int q = 0; q < QT; ++q) {
        float4 r1 = *(const float4*)&red[0][q][f4];
        float4 r2 = *(const float4*)&red[1][q][f4];
        float4 r3 = *(const float4*)&red[2][q][f4];
        c[q].x += (r1.x + r2.x) + r3.x;
        c[q].y += (r1.y + r2.y) + r3.y;
        c[q].z += (r1.z + r2.z) + r3.z;
        c[q].w += (r1.w + r2.w) + r3.w;
        *(float4*)(out_c + (size_t)(b * TD + q0 + q) * DE + f4) = c[q];
      }
    }
  }
}

extern "C" void kernel_launch(void* const* d_in, const int* in_sizes, int n_in,
                              void* d_out, int out_size, void* d_ws, size_t ws_size,
                              hipStream_t stream) {
  const float* enc = (const float*)d_in[0];
  const float* dec = (const float*)d_in[1];
  const float* Wa  = (const float*)d_in[2];
  const float* Ua  = (const float*)d_in[3];
  const float* Va  = (const float*)d_in[4];
  float* out_c = (float*)d_out;
  float* out_e = out_c + (size_t)NB * TD * DE;          // c first, then e

  // workspace layout (10 MB):
  float* ws = (float*)d_ws;                             // ew = e^{2Ws}: 4 MB
  float* uh = ws + 1048576;                             // eu = e^{2Uh}: 4 MB
  unsigned short* BHw = (unsigned short*)(uh + 1048576);// 0.5 MB each
  unsigned short* BLw = BHw + 262144;
  unsigned short* BHu = BLw + 262144;
  unsigned short* BLu = BHu + 262144;

  convB<<<dim3(16, 16, 2), dim3(256), 0, stream>>>(Wa, BHw, BLw, Ua, BHu, BLu);
  gemm_mfma<<<dim3(512), dim3(256), 0, stream>>>(
      enc, BHw, BLw, ws, dec, BHu, BLu, uh);
  attn<<<dim3(NB * (TD / QT)), dim3(512), 0, stream>>>(
      ws, uh, enc, Va, out_c, out_e);
}